// Round 7
// baseline (239.429 us; speedup 1.0000x reference)
//
#include <hip/hip_runtime.h>
#include <stdint.h>

typedef unsigned short u16;
typedef unsigned int   u32;
typedef unsigned long long u64;

#define F_DIM 256
#define O_DIM 24
#define MARGIN  3.0f      // capture margin (>= 2E bf16-vs-fp32 score bound; validated R2-R13)
#define FMARGIN 3.0f      // rescore global filter margin (same bound)
#define WCAP 512          // candidate slots per capture-wave (8 B each)
#define NWAVE_CAP 4096    // 8 mb * 64 chunks * 8 waves

#define AS1 __attribute__((address_space(1)))
#define AS3 __attribute__((address_space(3)))

typedef __bf16 bf16x8 __attribute__((ext_vector_type(8)));
typedef float  f32x4  __attribute__((ext_vector_type(4)));

__device__ __forceinline__ u32 ordf(float s) {
    u32 b = __float_as_uint(s);
    return (b & 0x80000000u) ? ~b : (b | 0x80000000u);
}
__device__ __forceinline__ u16 f2bf(float f) {   // round-to-nearest-even
    u32 u = __float_as_uint(f);
    u32 r = (u + 0x7FFFu + ((u >> 16) & 1u)) >> 16;
    return (u16)r;
}

// ---------------- init ----------------
__global__ void init_kernel(u64* best, int B) {
    int i = blockIdx.x * blockDim.x + threadIdx.x;
    if (i < B) best[i] = ~0ull;
}

// ---------------- t2 (fallback path only) ----------------
__global__ void t2_kernel(const float* __restrict__ X, float* __restrict__ t2,
                          int N, int Npad) {
    int tid = threadIdx.x;
    int row = blockIdx.x * 4 + (tid >> 6);
    int lane = tid & 63;
    if (row >= Npad) return;
    if (row >= N) { if (lane == 0) t2[row] = 1e30f; return; }
    float4 v = ((const float4*)(X + (size_t)row * F_DIM))[lane];
    float s = v.x * v.x + v.y * v.y + v.z * v.z + v.w * v.w;
    #pragma unroll
    for (int off = 32; off > 0; off >>= 1) s += __shfl_down(s, off, 64);
    if (lane == 0) t2[row] = s;
}

// ---------------- coalesced converter: fp32 row-major -> bf16 fragment order ----------------
__global__ __launch_bounds__(256) void convert_tile(const float* __restrict__ src,
        u16* __restrict__ dst, float* __restrict__ t2out, int nrows, int do_t2) {
    __shared__ u16 tl[8192];   // 16 KB
    const int tid = threadIdx.x;
    const int t = blockIdx.x, p = blockIdx.y;
    const int w = tid >> 6, L = tid & 63;
    const int col = L * 4;
    const int ks = col >> 5, j = col & 7, lhi = ((col >> 3) & 3) << 4;
    #pragma unroll
    for (int i = 0; i < 8; ++i) {
        int rloc = i * 4 + w;
        int grow = t * 128 + p * 32 + rloc;
        float4 v = make_float4(0.f, 0.f, 0.f, 0.f);
        if (grow < nrows) v = *(const float4*)(src + (size_t)grow * F_DIM + col);
        if (do_t2) {
            float s = v.x * v.x + v.y * v.y + v.z * v.z + v.w * v.w;
            #pragma unroll
            for (int off = 32; off > 0; off >>= 1) s += __shfl_down(s, off, 64);
            if (L == 0) t2out[grow] = (grow < nrows) ? s : 1e30f;
        }
        u16* q = &tl[ks * 1024 + (rloc >> 4) * 512 + (((rloc & 15) | lhi)) * 8 + j];
        q[0] = f2bf(v.x); q[1] = f2bf(v.y); q[2] = f2bf(v.z); q[3] = f2bf(v.w);
    }
    __syncthreads();
    const uint4* s4 = (const uint4*)tl;
    uint4* d4 = (uint4*)(dst + (size_t)t * 32768);
    #pragma unroll
    for (int v = 0; v < 4; ++v) {
        int lin = v * 256 + tid;
        int ksc = lin >> 7, subl = (lin >> 6) & 1, lane = lin & 63;
        d4[(ksc * 8 + 2 * p + subl) * 64 + lane] = s4[lin];
    }
}

// ---------------- main: R6 = counted-vmcnt pipeline (T3/T4), 4-buffer ring, 1 raw barrier/iter ----------------
// R5 closed the traffic story: FETCH 17 MB, WRITE 8.5 MB (compulsory), spill-free
// (VGPR 88). Residual: ~4K cyc/iter exposed stall = __syncthreads' vmcnt(0) drain of
// the just-issued prefetch + per-iter t2 loads, x2 because BN=32 doubled barriers.
// R6: (a) 4 x 16 KB LDS ring, prefetch depth 2; (b) per-iter sync = counted
// `s_waitcnt vmcnt(4)` (keeps stages nt+1,nt+2 in flight; in-order retirement =>
// stage-nt landed since >=4 newer ops exist) + RAW s_barrier + sched_barrier(0)
// (pins ds_reads after barrier; cross-wave staging covered by each wave's own wait
// before ITS barrier arrival); (c) t2 chunk-slice cached in LDS once (3.2 KB) so the
// vmcnt stream holds ONLY stage loads (else compiler's t2-use wait would drain the
// prefetch). Buffer reuse safe: stage at iter nt writes buf[(nt-2)&3], last read in
// compute nt-2, finished by all waves before barrier nt-1. Tail: vmcnt(2)/vmcnt(0).
// (R6 resubmission: previous round was a GPUAcquisitionTimeout, kernel never ran.)
__global__ __launch_bounds__(512, 2) void knn_mfma(
    const u16* __restrict__ xbf, const u16* __restrict__ xtbf,
    const float* __restrict__ t2, float* __restrict__ chunkmin,
    u32* __restrict__ wavecnt, u64* __restrict__ cands,
    int ntiles /*32-col tiles*/, int nch)
{
    __shared__ u16 sB[4][8192];   // 4 x 16 KB ring (32-col half-tiles)
    __shared__ float sT2[800];    // chunk t2 slice (<= 25 tiles * 32)

    const int tid = threadIdx.x;
    const int L = tid & 63, w = tid >> 6;   // 8 waves
    const int lid = blockIdx.x;
    const int mbcnt = (int)(gridDim.x) / nch;
    int mb, chunk;
    if (nch == 64 && mbcnt == 8) {
        const int xg = lid & 7, slot = lid >> 3;
        chunk = xg * 8 + (slot >> 3);       // 8 chunks per XCD (round-robin or contiguous)
        mb = slot & 7;
    } else {
        mb = lid % mbcnt;                   // legacy linearization
        chunk = lid / mbcnt;
    }
    const int gwave = (mb * 64 + chunk) * 8 + w;
    const int t0 = (int)(((long long)chunk * ntiles) / nch);
    const int t1 = (int)(((long long)(chunk + 1) * ntiles) / nch);

    // nt is a 32-col half-tile: nt64 = nt>>1, half = nt&1
    #define TBASE_U32(nt) ((const AS1 u32*)xtbf + (size_t)((nt) >> 2) * 16384 \
                           + (size_t)(((nt) >> 1) & 1) * 1024 + (size_t)((nt) & 1) * 512)

    // ---- stage one 16 KB half-tile (async, 2 x 512 threads x 16 B) ----
    #define STAGE(buf, nt) do {                                                        \
        const AS1 u32* gp_ = TBASE_U32(nt);                                            \
        AS3 u32* lb_ = (AS3 u32*)&sB[buf][0];                                          \
        _Pragma("unroll")                                                              \
        for (int j = 0; j < 2; ++j) {                                                  \
            const int unit = j * 8 + w;                                                \
            __builtin_amdgcn_global_load_lds(                                          \
                gp_ + (size_t)(unit >> 1) * 2048 + (size_t)(unit & 1) * 256            \
                    + (size_t)L * 4,                                                   \
                lb_ + unit * 256, 16, 0, 0);                                           \
        }                                                                              \
    } while (0)

    // ---- prologue: stage t0, t0+1 (async) + t2 slice -> LDS + A fragments ----
    STAGE(t0 & 3, t0);
    if (t0 + 1 < t1) STAGE((t0 + 1) & 3, t0 + 1);

    {
        const int cnt = (t1 - t0) * 32;
        for (int k = tid; k < cnt; k += 512) sT2[k] = t2[t0 * 32 + k];
    }

    bf16x8 areg[16];
    {
        const int t128 = mb * 2 + (w >> 2);
        const u16* base = xbf + (size_t)t128 * 32768 + (size_t)(w & 3) * 1024 + (size_t)L * 8;
        #pragma unroll
        for (int ks = 0; ks < 8; ++ks)
            #pragma unroll
            for (int i = 0; i < 2; ++i)
                areg[ks * 2 + i] = *(const bf16x8*)(base + ks * 4096 + i * 512);
    }

    float rowmin_reg[2][4];
    #pragma unroll
    for (int i = 0; i < 2; ++i)
        #pragma unroll
        for (int r = 0; r < 4; ++r) rowmin_reg[i][r] = 1e30f;

    u32 wcount = 0;
    u64* const wreg = cands + (size_t)gwave * WCAP;

    __syncthreads();   // one-time full drain: prologue stages + t2 ds_writes + areg

    for (int nt = t0; nt < t1; ++nt) {
        const int cur = nt & 3;
        // issue prefetch, then COUNTED wait (never 0 mid-loop) + raw barrier
        if (nt + 2 < t1) {
            STAGE((nt + 2) & 3, nt + 2);
            asm volatile("s_waitcnt vmcnt(4)" ::: "memory");
        } else if (nt + 1 < t1) {
            asm volatile("s_waitcnt vmcnt(2)" ::: "memory");
        } else {
            asm volatile("s_waitcnt vmcnt(0)" ::: "memory");
        }
        __builtin_amdgcn_s_barrier();
        asm volatile("" ::: "memory");
        __builtin_amdgcn_sched_barrier(0);

        float t2v[2];
        #pragma unroll
        for (int c = 0; c < 2; ++c) t2v[c] = sT2[(nt - t0) * 32 + (L & 15) + c * 16];

        f32x4 acc[2][2];
        #pragma unroll
        for (int i = 0; i < 2; ++i)
            #pragma unroll
            for (int c = 0; c < 2; ++c)
                #pragma unroll
                for (int r = 0; r < 4; ++r) acc[i][c][r] = 0.f;

        #pragma unroll
        for (int ks = 0; ks < 8; ++ks) {
            bf16x8 bc[2];
            #pragma unroll
            for (int c = 0; c < 2; ++c)
                bc[c] = *(const bf16x8*)&sB[cur][ks * 1024 + c * 512 + L * 8];
            #pragma unroll
            for (int i = 0; i < 2; ++i)
                #pragma unroll
                for (int c = 0; c < 2; ++c)
                    acc[i][c] = __builtin_amdgcn_mfma_f32_16x16x32_bf16(areg[ks * 2 + i], bc[c], acc[i][c], 0, 0, 0);
        }

        // ---- epilogue ----
        const int colb = nt * 32 + (L & 15);
        float r4[2][4];
        #pragma unroll
        for (int i = 0; i < 2; ++i) {
            #pragma unroll
            for (int r = 0; r < 4; ++r) r4[i][r] = 1e30f;
            #pragma unroll
            for (int c = 0; c < 2; ++c)
                #pragma unroll
                for (int r = 0; r < 4; ++r)
                    r4[i][r] = fminf(r4[i][r], fmaf(-2.f, acc[i][c][r], t2v[c]));
        }

        // threshold base (subset-min of the row's bf16 scores: safe with MARGIN >= 2E)
        float thb[2][4];
        if (nt == t0) {
            // seed: butterfly tile-t0 row-min FIRST so t0 capture doesn't flood
            #pragma unroll
            for (int i = 0; i < 2; ++i)
                #pragma unroll
                for (int r = 0; r < 4; ++r) rowmin_reg[i][r] = r4[i][r];
            #pragma unroll
            for (int st = 1; st <= 8; st <<= 1)
                #pragma unroll
                for (int i = 0; i < 2; ++i)
                    #pragma unroll
                    for (int r = 0; r < 4; ++r)
                        rowmin_reg[i][r] = fminf(rowmin_reg[i][r], __shfl_xor(rowmin_reg[i][r], st, 64));
            #pragma unroll
            for (int i = 0; i < 2; ++i)
                #pragma unroll
                for (int r = 0; r < 4; ++r) thb[i][r] = rowmin_reg[i][r];
        } else {
            #pragma unroll
            for (int i = 0; i < 2; ++i)
                #pragma unroll
                for (int r = 0; r < 4; ++r) thb[i][r] = fminf(rowmin_reg[i][r], r4[i][r]);
        }

        bool anyhit = false;
        #pragma unroll
        for (int i = 0; i < 2; ++i)
            #pragma unroll
            for (int r = 0; r < 4; ++r)
                anyhit = anyhit || (r4[i][r] < thb[i][r] + MARGIN);

        if (__any(anyhit)) {
            u32 cnt = 0;
            #pragma unroll
            for (int i = 0; i < 2; ++i)
                #pragma unroll
                for (int r = 0; r < 4; ++r) {
                    float th = thb[i][r] + MARGIN;
                    if (r4[i][r] < th) {
                        #pragma unroll
                        for (int c = 0; c < 2; ++c)
                            cnt += (fmaf(-2.f, acc[i][c][r], t2v[c]) < th) ? 1u : 0u;
                    }
                }
            u32 pre = cnt;
            #pragma unroll
            for (int d = 1; d < 64; d <<= 1) {
                u32 v = __shfl_up(pre, d, 64);
                if (L >= d) pre += v;
            }
            u32 total = __shfl(pre, 63, 64);
            u32 woff = wcount + pre - cnt;
            #pragma unroll
            for (int i = 0; i < 2; ++i)
                #pragma unroll
                for (int r = 0; r < 4; ++r) {
                    float th = thb[i][r] + MARGIN;
                    if (r4[i][r] < th) {
                        const int q = mb * 256 + w * 32 + i * 16 + (L >> 4) * 4 + r;
                        #pragma unroll
                        for (int c = 0; c < 2; ++c) {
                            float s = fmaf(-2.f, acc[i][c][r], t2v[c]);
                            if (s < th) {
                                if (woff < WCAP)
                                    wreg[woff] = ((u64)__float_as_uint(s) << 32)
                                               | (u64)(((u32)q << 16) | (u32)(colb + c * 16));
                                woff++;
                            }
                        }
                    }
                }
            wcount += total;
        }

        // fold per-lane; full 16-lane butterfly only every 4th tile
        #pragma unroll
        for (int i = 0; i < 2; ++i)
            #pragma unroll
            for (int r = 0; r < 4; ++r)
                rowmin_reg[i][r] = fminf(rowmin_reg[i][r], r4[i][r]);
        if (((nt - t0) & 3) == 3) {
            #pragma unroll
            for (int st = 1; st <= 8; st <<= 1)
                #pragma unroll
                for (int i = 0; i < 2; ++i)
                    #pragma unroll
                    for (int r = 0; r < 4; ++r)
                        rowmin_reg[i][r] = fminf(rowmin_reg[i][r], __shfl_xor(rowmin_reg[i][r], st, 64));
        }
        // no end-of-iter __syncthreads: single raw barrier per iteration (top)
    }

    // ---- final: exact chunk row-min + candidate count ----
    #pragma unroll
    for (int st = 1; st <= 8; st <<= 1)
        #pragma unroll
        for (int i = 0; i < 2; ++i)
            #pragma unroll
            for (int r = 0; r < 4; ++r)
                rowmin_reg[i][r] = fminf(rowmin_reg[i][r], __shfl_xor(rowmin_reg[i][r], st, 64));
    if ((L & 15) == 0) {
        #pragma unroll
        for (int i = 0; i < 2; ++i)
            #pragma unroll
            for (int r = 0; r < 4; ++r) {
                int q = mb * 256 + w * 32 + i * 16 + (L >> 4) * 4 + r;
                chunkmin[(size_t)q * nch + chunk] = rowmin_reg[i][r];
            }
    }
    if (L == 0) wavecnt[gwave] = (wcount < WCAP) ? wcount : WCAP;
    #undef STAGE
    #undef TBASE_U32
}

// ---------------- global bf16 row-min: gmin[q] = min over chunks ----------------
__global__ void reduce_gmin(const float* __restrict__ chunkmin, float* __restrict__ gmin,
                            int B, int nch) {
    const int q = blockIdx.x * 4 + (threadIdx.x >> 6);
    const int c = threadIdx.x & 63;
    if (q >= B) return;
    float v = (c < nch) ? chunkmin[(size_t)q * nch + c] : 1e30f;
    #pragma unroll
    for (int st = 1; st < 64; st <<= 1) v = fminf(v, __shfl_xor(v, st, 64));
    if (c == 0) gmin[q] = v;
}

// ---------------- filtered exact fp32 rescore: ballot-compacted, wave-cooperative ----------------
__global__ void rescore(const float* __restrict__ x, const float* __restrict__ Xt,
                        const float* __restrict__ t2, const float* __restrict__ gmin,
                        const u32* __restrict__ wavecnt, const u64* __restrict__ cands,
                        u64* __restrict__ best) {
    const int L = threadIdx.x & 63;
    const int gw = blockIdx.x * (blockDim.x >> 6) + (threadIdx.x >> 6);
    if (gw >= NWAVE_CAP) return;
    u32 cnt = wavecnt[gw];
    if (cnt > WCAP) cnt = WCAP;
    const u64* reg = cands + (size_t)gw * WCAP;
    for (u32 base = 0; base < cnt; base += 64) {
        u32 i = base + L;
        u64 rec = 0; bool pass = false;
        if (i < cnt) {
            rec = reg[i];                                   // coalesced 512 B
            float sb = __uint_as_float((u32)(rec >> 32));
            int q = (int)((rec >> 16) & 0xFFFFu);
            pass = sb < gmin[q] + FMARGIN;
        }
        u64 bal = __ballot(pass);
        while (bal) {
            int j = __ffsll((unsigned long long)bal) - 1;
            bal &= bal - 1;
            u64 r2 = __shfl(rec, j, 64);
            int q = (int)((r2 >> 16) & 0xFFFFu);
            int n = (int)(r2 & 0xFFFFu);
            float4 a = *((const float4*)(x  + (size_t)q * F_DIM) + L);
            float4 b = *((const float4*)(Xt + (size_t)n * F_DIM) + L);
            float d = fmaf(a.x, b.x, fmaf(a.y, b.y, fmaf(a.z, b.z, a.w * b.w)));
            #pragma unroll
            for (int st = 32; st > 0; st >>= 1) d += __shfl_xor(d, st, 64);
            if (L == 0) {
                float s = fmaf(-2.f, d, t2[n]);
                u64 p = ((u64)ordf(s) << 32) | (u32)n;
                atomicMin(&best[q], p);
            }
        }
    }
}

// ---------------- gather Y[nearest] ----------------
__global__ void gather_kernel(const float* __restrict__ Y, const u64* __restrict__ best,
                              float* __restrict__ out, int B, int N) {
    int gid = blockIdx.x * blockDim.x + threadIdx.x;
    int total = B * O_DIM;
    if (gid >= total) return;
    int b = gid / O_DIM;
    int o = gid - b * O_DIM;
    u32 n = (u32)(best[b] & 0xFFFFFFFFull);
    if (n >= (u32)N) n = 0;   // defensive
    out[gid] = Y[(size_t)n * O_DIM + o];
}

// ================= fp32 fallback (proven Round-1 path, used if ws too small) =================
#define BM 128
#define BN 128
#define BK 16
#define NSPLIT 64
#define LDA (BM + 4)

__global__ __launch_bounds__(256) void knn_main_fp32(
    const float* __restrict__ Xq, const float* __restrict__ Xt,
    const float* __restrict__ t2, u64* __restrict__ best, int N)
{
    __shared__ float As[BK][LDA];
    __shared__ float Bs[BK][LDA];
    __shared__ u64 red[BM][17];

    const int tid = threadIdx.x;
    const int tx = tid & 15;
    const int ty = tid >> 4;
    const int m0 = blockIdx.y * BM;
    const int CHUNK = (N + NSPLIT - 1) / NSPLIT;
    const int n0c = blockIdx.x * CHUNK;
    const int n1c = min(N, n0c + CHUNK);

    u64 bestv[8];
    #pragma unroll
    for (int i = 0; i < 8; ++i) bestv[i] = ~0ull;

    const int srow = tid >> 2;
    const int scol4 = (tid & 3) * 4;

    for (int nt = n0c; nt < n1c; nt += BN) {
        float accl[8][8];
        #pragma unroll
        for (int i = 0; i < 8; ++i)
            #pragma unroll
            for (int j = 0; j < 8; ++j) accl[i][j] = 0.f;
        for (int k0 = 0; k0 < F_DIM; k0 += BK) {
            #pragma unroll
            for (int h = 0; h < 2; ++h) {
                int row = h * 64 + srow;
                float4 av = *(const float4*)(Xq + (size_t)(m0 + row) * F_DIM + k0 + scol4);
                As[scol4 + 0][row] = av.x; As[scol4 + 1][row] = av.y;
                As[scol4 + 2][row] = av.z; As[scol4 + 3][row] = av.w;
                int n = nt + row;
                float4 bv = make_float4(0.f, 0.f, 0.f, 0.f);
                if (n < n1c) bv = *(const float4*)(Xt + (size_t)n * F_DIM + k0 + scol4);
                Bs[scol4 + 0][row] = bv.x; Bs[scol4 + 1][row] = bv.y;
                Bs[scol4 + 2][row] = bv.z; Bs[scol4 + 3][row] = bv.w;
            }
            __syncthreads();
            #pragma unroll
            for (int k = 0; k < BK; ++k) {
                float4 a0 = *(const float4*)&As[k][ty * 4];
                float4 a1 = *(const float4*)&As[k][64 + ty * 4];
                float4 b0 = *(const float4*)&Bs[k][tx * 4];
                float4 b1 = *(const float4*)&Bs[k][64 + tx * 4];
                float am[8] = {a0.x, a0.y, a0.z, a0.w, a1.x, a1.y, a1.z, a1.w};
                float bn[8] = {b0.x, b0.y, b0.z, b0.w, b1.x, b1.y, b1.z, b1.w};
                #pragma unroll
                for (int i = 0; i < 8; ++i)
                    #pragma unroll
                    for (int j = 0; j < 8; ++j)
                        accl[i][j] = fmaf(am[i], bn[j], accl[i][j]);
            }
            __syncthreads();
        }
        #pragma unroll
        for (int j = 0; j < 8; ++j) {
            int nl = (j < 4) ? (tx * 4 + j) : (64 + tx * 4 + (j - 4));
            int n = nt + nl;
            if (n < n1c) {
                float t2v = t2[n];
                #pragma unroll
                for (int i = 0; i < 8; ++i) {
                    float score = fmaf(-2.f, accl[i][j], t2v);
                    u64 p = ((u64)ordf(score) << 32) | (u32)n;
                    bestv[i] = (p < bestv[i]) ? p : bestv[i];
                }
            }
        }
    }
    #pragma unroll
    for (int i = 0; i < 8; ++i) {
        int ml = (i < 4) ? (ty * 4 + i) : (64 + ty * 4 + (i - 4));
        red[ml][tx] = bestv[i];
    }
    __syncthreads();
    if (tid < BM) {
        u64 b = red[tid][0];
        #pragma unroll
        for (int t = 1; t < 16; ++t) { u64 v = red[tid][t]; b = (v < b) ? v : b; }
        atomicMin(&best[m0 + tid], b);
    }
}

// ================= launch =================
extern "C" void kernel_launch(void* const* d_in, const int* in_sizes, int n_in,
                              void* d_out, int out_size, void* d_ws, size_t ws_size,
                              hipStream_t stream) {
    const float* x  = (const float*)d_in[0];
    const float* Xt = (const float*)d_in[1];
    const float* Yt = (const float*)d_in[2];
    float* out = (float*)d_out;

    const int B = in_sizes[0] / F_DIM;        // 2048
    const int N = in_sizes[1] / F_DIM;        // 50000
    const int NT128 = (N + 127) / 128;        // 391
    const int Npad = NT128 * 128;             // 50048
    const int NT64 = NT128 * 2;               // 782
    const int NT32 = NT64 * 2;                // 1564
    const int MB = B / 256;                   // 8
    const int MT128 = B / 128;                // 16
    const int NCH = 64;                       // 8*64 = 512 blocks = 2/CU (512 thr each)

    char* wsp = (char*)d_ws;
    size_t off = 0;
    auto nxt = [&](size_t bytes) {
        char* p = wsp + off;
        off = (off + bytes + 255) & ~(size_t)255;
        return p;
    };
    float* t2       = (float*)nxt((size_t)Npad * 4);
    u64*   best     = (u64*)  nxt((size_t)B * 8);
    u32*   wavecnt  = (u32*)  nxt((size_t)NWAVE_CAP * 4);
    float* gmin     = (float*)nxt((size_t)B * 4);
    float* chunkmin = (float*)nxt((size_t)B * NCH * 4);
    u64*   cands    = (u64*)  nxt((size_t)NWAVE_CAP * WCAP * 8);
    u16*   xbf      = (u16*)  nxt((size_t)B * F_DIM * 2);
    u16*   xtbf     = (u16*)  nxt((size_t)Npad * F_DIM * 2);
    size_t required = off;

    init_kernel<<<(B + 255) / 256, 256, 0, stream>>>(best, B);

    if (ws_size >= required && B % 256 == 0 && MB * NCH * 8 <= NWAVE_CAP) {
        convert_tile<<<dim3(MT128, 4), 256, 0, stream>>>(x, xbf, (float*)nullptr, B, 0);
        convert_tile<<<dim3(NT128, 4), 256, 0, stream>>>(Xt, xtbf, t2, N, 1);   // fused t2
        knn_mfma<<<dim3(MB * NCH), 512, 0, stream>>>(xbf, xtbf, t2, chunkmin, wavecnt, cands, NT32, NCH);
        reduce_gmin<<<(B + 3) / 4, 256, 0, stream>>>(chunkmin, gmin, B, NCH);
        rescore<<<NWAVE_CAP / 4, 256, 0, stream>>>(x, Xt, t2, gmin, wavecnt, cands, best);
    } else {
        t2_kernel<<<(N + 3) / 4, 256, 0, stream>>>(Xt, t2, N, N);
        dim3 grid(NSPLIT, B / BM);
        knn_main_fp32<<<grid, 256, 0, stream>>>(x, Xt, t2, best, N);
    }

    int total = B * O_DIM;
    gather_kernel<<<(total + 255) / 256, 256, 0, stream>>>(Yt, best, out, B, N);
}

// Round 8
// 234.265 us; speedup vs baseline: 1.0220x; 1.0220x over previous
//
#include <hip/hip_runtime.h>
#include <stdint.h>

typedef unsigned short u16;
typedef unsigned int   u32;
typedef unsigned long long u64;

#define F_DIM 256
#define O_DIM 24
#define MARGIN  3.0f      // capture margin (>= 2E bf16-vs-fp32 score bound; validated R2-R13)
#define FMARGIN 3.0f      // rescore global filter margin (same bound)
#define WCAP 512          // candidate slots per capture-wave (8 B each)
#define NWAVE_CAP 4096    // 8 mb * 64 chunks * 8 waves

#define AS1 __attribute__((address_space(1)))
#define AS3 __attribute__((address_space(3)))

typedef __bf16 bf16x8 __attribute__((ext_vector_type(8)));
typedef float  f32x4  __attribute__((ext_vector_type(4)));

__device__ __forceinline__ u32 ordf(float s) {
    u32 b = __float_as_uint(s);
    return (b & 0x80000000u) ? ~b : (b | 0x80000000u);
}
__device__ __forceinline__ float iordf(u32 e) {   // inverse of ordf
    return __uint_as_float((e & 0x80000000u) ? (e ^ 0x80000000u) : ~e);
}
__device__ __forceinline__ u16 f2bf(float f) {   // round-to-nearest-even
    u32 u = __float_as_uint(f);
    u32 r = (u + 0x7FFFu + ((u >> 16) & 1u)) >> 16;
    return (u16)r;
}

// ---------------- init (fallback path only; main path inits inside convert_x) ----------------
__global__ void init_kernel(u64* best, u32* gminu, int B) {
    int i = blockIdx.x * blockDim.x + threadIdx.x;
    if (i < B) { best[i] = ~0ull; if (gminu) gminu[i] = ordf(1e30f); }
}

// ---------------- t2 (fallback path only) ----------------
__global__ void t2_kernel(const float* __restrict__ X, float* __restrict__ t2,
                          int N, int Npad) {
    int tid = threadIdx.x;
    int row = blockIdx.x * 4 + (tid >> 6);
    int lane = tid & 63;
    if (row >= Npad) return;
    if (row >= N) { if (lane == 0) t2[row] = 1e30f; return; }
    float4 v = ((const float4*)(X + (size_t)row * F_DIM))[lane];
    float s = v.x * v.x + v.y * v.y + v.z * v.z + v.w * v.w;
    #pragma unroll
    for (int off = 32; off > 0; off >>= 1) s += __shfl_down(s, off, 64);
    if (lane == 0) t2[row] = s;
}

// ---------------- coalesced converter: fp32 row-major -> bf16 fragment order ----------------
// R8: optional fused init of best/gminu (saves the init_kernel launch on the main path).
__global__ __launch_bounds__(256) void convert_tile(const float* __restrict__ src,
        u16* __restrict__ dst, float* __restrict__ t2out, int nrows, int do_t2,
        u64* best, u32* gminu, int ninit) {
    __shared__ u16 tl[8192];   // 16 KB
    const int tid = threadIdx.x;
    const int t = blockIdx.x, p = blockIdx.y;
    if (best) {
        int id = (p * gridDim.x + t) * 256 + tid;
        if (id < ninit) { best[id] = ~0ull; gminu[id] = ordf(1e30f); }
    }
    const int w = tid >> 6, L = tid & 63;
    const int col = L * 4;
    const int ks = col >> 5, j = col & 7, lhi = ((col >> 3) & 3) << 4;
    #pragma unroll
    for (int i = 0; i < 8; ++i) {
        int rloc = i * 4 + w;
        int grow = t * 128 + p * 32 + rloc;
        float4 v = make_float4(0.f, 0.f, 0.f, 0.f);
        if (grow < nrows) v = *(const float4*)(src + (size_t)grow * F_DIM + col);
        if (do_t2) {
            float s = v.x * v.x + v.y * v.y + v.z * v.z + v.w * v.w;
            #pragma unroll
            for (int off = 32; off > 0; off >>= 1) s += __shfl_down(s, off, 64);
            if (L == 0) t2out[grow] = (grow < nrows) ? s : 1e30f;
        }
        u16* q = &tl[ks * 1024 + (rloc >> 4) * 512 + (((rloc & 15) | lhi)) * 8 + j];
        q[0] = f2bf(v.x); q[1] = f2bf(v.y); q[2] = f2bf(v.z); q[3] = f2bf(v.w);
    }
    __syncthreads();
    const uint4* s4 = (const uint4*)tl;
    uint4* d4 = (uint4*)(dst + (size_t)t * 32768);
    #pragma unroll
    for (int v = 0; v < 4; ++v) {
        int lin = v * 256 + tid;
        int ksc = lin >> 7, subl = (lin >> 6) & 1, lane = lin & 63;
        d4[(ksc * 8 + 2 * p + subl) * 64 + lane] = s4[lin];
    }
}

// ---------------- main: R8 = exact R5 loop body (proven 126 us) + fused gmin atomics ----------------
// R7 post-mortem: counted-vmcnt + sched_barrier(0) pipeline REGRESSED 126->143 us.
// (a) sched_barrier(0) order-pinning defeats the compiler's own scheduling (guide m141);
// (b) vmcnt(4) is polluted by in-flight candidate stores: vmem retires in-order, so
// reaching <=4 outstanding forces waiting on epilogue stores + the nt+1 stage loads.
// Theory "barrier drain = the per-iter stall" is REFUTED; R5's compiler-scheduled
// structure is the best of this family. R8 reverts the loop to R5 byte-for-byte and
// only changes the FINAL section: chunkmin write + reduce_gmin kernel replaced by
// atomicMin(&gminu[q], ordf(rowmin)) (131K atomics to 2048 words; removes one kernel
// launch + the 512 KB chunkmin round-trip).
__global__ __launch_bounds__(512, 2) void knn_mfma(
    const u16* __restrict__ xbf, const u16* __restrict__ xtbf,
    const float* __restrict__ t2, u32* __restrict__ gminu,
    u32* __restrict__ wavecnt, u64* __restrict__ cands,
    int ntiles /*32-col tiles*/, int nch)
{
    __shared__ u16 sB[2][8192];   // 2 x 16 KB (32-col half-tiles)

    const int tid = threadIdx.x;
    const int L = tid & 63, w = tid >> 6;   // 8 waves
    const int lid = blockIdx.x;
    const int mbcnt = (int)(gridDim.x) / nch;
    int mb, chunk;
    if (nch == 64 && mbcnt == 8) {
        const int xg = lid & 7, slot = lid >> 3;
        chunk = xg * 8 + (slot >> 3);       // 8 chunks per XCD (round-robin or contiguous)
        mb = slot & 7;
    } else {
        mb = lid % mbcnt;                   // legacy linearization
        chunk = lid / mbcnt;
    }
    const int gwave = (mb * 64 + chunk) * 8 + w;
    const int t0 = (int)(((long long)chunk * ntiles) / nch);
    const int t1 = (int)(((long long)(chunk + 1) * ntiles) / nch);

    // nt is a 32-col half-tile: nt64 = nt>>1, half = nt&1
    #define TBASE_U32(nt) ((const AS1 u32*)xtbf + (size_t)((nt) >> 2) * 16384 \
                           + (size_t)(((nt) >> 1) & 1) * 1024 + (size_t)((nt) & 1) * 512)

    // ---- stage one 16 KB half-tile (async, 2 x 512 threads x 16 B) ----
    #define STAGE(buf, nt) do {                                                        \
        const AS1 u32* gp_ = TBASE_U32(nt);                                            \
        AS3 u32* lb_ = (AS3 u32*)&sB[buf][0];                                          \
        _Pragma("unroll")                                                              \
        for (int j = 0; j < 2; ++j) {                                                  \
            const int unit = j * 8 + w;                                                \
            __builtin_amdgcn_global_load_lds(                                          \
                gp_ + (size_t)(unit >> 1) * 2048 + (size_t)(unit & 1) * 256            \
                    + (size_t)L * 4,                                                   \
                lb_ + unit * 256, 16, 0, 0);                                           \
        }                                                                              \
    } while (0)

    STAGE(0, t0);

    // ---- A fragments in registers: wave w owns rows mb*256 + w*32 .. +31 ----
    bf16x8 areg[16];
    {
        const int t128 = mb * 2 + (w >> 2);
        const u16* base = xbf + (size_t)t128 * 32768 + (size_t)(w & 3) * 1024 + (size_t)L * 8;
        #pragma unroll
        for (int ks = 0; ks < 8; ++ks)
            #pragma unroll
            for (int i = 0; i < 2; ++i)
                areg[ks * 2 + i] = *(const bf16x8*)(base + ks * 4096 + i * 512);
    }

    float rowmin_reg[2][4];
    #pragma unroll
    for (int i = 0; i < 2; ++i)
        #pragma unroll
        for (int r = 0; r < 4; ++r) rowmin_reg[i][r] = 1e30f;

    u32 wcount = 0;
    u64* const wreg = cands + (size_t)gwave * WCAP;

    __syncthreads();   // first half-tile staged

    for (int nt = t0; nt < t1; ++nt) {
        const int cur = (nt - t0) & 1;
        if (nt + 1 < t1) STAGE(cur ^ 1, nt + 1);   // prefetch into other buffer

        float t2v[2];
        #pragma unroll
        for (int c = 0; c < 2; ++c) t2v[c] = t2[nt * 32 + (L & 15) + c * 16];

        f32x4 acc[2][2];
        #pragma unroll
        for (int i = 0; i < 2; ++i)
            #pragma unroll
            for (int c = 0; c < 2; ++c)
                #pragma unroll
                for (int r = 0; r < 4; ++r) acc[i][c][r] = 0.f;

        #pragma unroll
        for (int ks = 0; ks < 8; ++ks) {
            bf16x8 bc[2];
            #pragma unroll
            for (int c = 0; c < 2; ++c)
                bc[c] = *(const bf16x8*)&sB[cur][ks * 1024 + c * 512 + L * 8];
            #pragma unroll
            for (int i = 0; i < 2; ++i)
                #pragma unroll
                for (int c = 0; c < 2; ++c)
                    acc[i][c] = __builtin_amdgcn_mfma_f32_16x16x32_bf16(areg[ks * 2 + i], bc[c], acc[i][c], 0, 0, 0);
        }

        // ---- epilogue ----
        const int colb = nt * 32 + (L & 15);
        float r4[2][4];
        #pragma unroll
        for (int i = 0; i < 2; ++i) {
            #pragma unroll
            for (int r = 0; r < 4; ++r) r4[i][r] = 1e30f;
            #pragma unroll
            for (int c = 0; c < 2; ++c)
                #pragma unroll
                for (int r = 0; r < 4; ++r)
                    r4[i][r] = fminf(r4[i][r], fmaf(-2.f, acc[i][c][r], t2v[c]));
        }

        // threshold base (subset-min of the row's bf16 scores: safe with MARGIN >= 2E)
        float thb[2][4];
        if (nt == t0) {
            // seed: butterfly tile-t0 row-min FIRST so t0 capture doesn't flood
            #pragma unroll
            for (int i = 0; i < 2; ++i)
                #pragma unroll
                for (int r = 0; r < 4; ++r) rowmin_reg[i][r] = r4[i][r];
            #pragma unroll
            for (int st = 1; st <= 8; st <<= 1)
                #pragma unroll
                for (int i = 0; i < 2; ++i)
                    #pragma unroll
                    for (int r = 0; r < 4; ++r)
                        rowmin_reg[i][r] = fminf(rowmin_reg[i][r], __shfl_xor(rowmin_reg[i][r], st, 64));
            #pragma unroll
            for (int i = 0; i < 2; ++i)
                #pragma unroll
                for (int r = 0; r < 4; ++r) thb[i][r] = rowmin_reg[i][r];
        } else {
            #pragma unroll
            for (int i = 0; i < 2; ++i)
                #pragma unroll
                for (int r = 0; r < 4; ++r) thb[i][r] = fminf(rowmin_reg[i][r], r4[i][r]);
        }

        bool anyhit = false;
        #pragma unroll
        for (int i = 0; i < 2; ++i)
            #pragma unroll
            for (int r = 0; r < 4; ++r)
                anyhit = anyhit || (r4[i][r] < thb[i][r] + MARGIN);

        if (__any(anyhit)) {
            u32 cnt = 0;
            #pragma unroll
            for (int i = 0; i < 2; ++i)
                #pragma unroll
                for (int r = 0; r < 4; ++r) {
                    float th = thb[i][r] + MARGIN;
                    if (r4[i][r] < th) {
                        #pragma unroll
                        for (int c = 0; c < 2; ++c)
                            cnt += (fmaf(-2.f, acc[i][c][r], t2v[c]) < th) ? 1u : 0u;
                    }
                }
            u32 pre = cnt;
            #pragma unroll
            for (int d = 1; d < 64; d <<= 1) {
                u32 v = __shfl_up(pre, d, 64);
                if (L >= d) pre += v;
            }
            u32 total = __shfl(pre, 63, 64);
            u32 woff = wcount + pre - cnt;
            #pragma unroll
            for (int i = 0; i < 2; ++i)
                #pragma unroll
                for (int r = 0; r < 4; ++r) {
                    float th = thb[i][r] + MARGIN;
                    if (r4[i][r] < th) {
                        const int q = mb * 256 + w * 32 + i * 16 + (L >> 4) * 4 + r;
                        #pragma unroll
                        for (int c = 0; c < 2; ++c) {
                            float s = fmaf(-2.f, acc[i][c][r], t2v[c]);
                            if (s < th) {
                                if (woff < WCAP)
                                    wreg[woff] = ((u64)__float_as_uint(s) << 32)
                                               | (u64)(((u32)q << 16) | (u32)(colb + c * 16));
                                woff++;
                            }
                        }
                    }
                }
            wcount += total;
        }

        // fold per-lane; full 16-lane butterfly only every 4th tile
        #pragma unroll
        for (int i = 0; i < 2; ++i)
            #pragma unroll
            for (int r = 0; r < 4; ++r)
                rowmin_reg[i][r] = fminf(rowmin_reg[i][r], r4[i][r]);
        if (((nt - t0) & 3) == 3) {
            #pragma unroll
            for (int st = 1; st <= 8; st <<= 1)
                #pragma unroll
                for (int i = 0; i < 2; ++i)
                    #pragma unroll
                    for (int r = 0; r < 4; ++r)
                        rowmin_reg[i][r] = fminf(rowmin_reg[i][r], __shfl_xor(rowmin_reg[i][r], st, 64));
        }

        __syncthreads();   // drains next-tile stage + protects buffer reuse
    }

    // ---- final: exact chunk row-min -> global gmin atomics + candidate count ----
    #pragma unroll
    for (int st = 1; st <= 8; st <<= 1)
        #pragma unroll
        for (int i = 0; i < 2; ++i)
            #pragma unroll
            for (int r = 0; r < 4; ++r)
                rowmin_reg[i][r] = fminf(rowmin_reg[i][r], __shfl_xor(rowmin_reg[i][r], st, 64));
    if ((L & 15) == 0) {
        #pragma unroll
        for (int i = 0; i < 2; ++i)
            #pragma unroll
            for (int r = 0; r < 4; ++r) {
                int q = mb * 256 + w * 32 + i * 16 + (L >> 4) * 4 + r;
                atomicMin(&gminu[q], ordf(rowmin_reg[i][r]));
            }
    }
    if (L == 0) wavecnt[gwave] = (wcount < WCAP) ? wcount : WCAP;
    #undef STAGE
    #undef TBASE_U32
}

// ---------------- filtered exact fp32 rescore: ballot-compacted, wave-cooperative ----------------
__global__ void rescore(const float* __restrict__ x, const float* __restrict__ Xt,
                        const float* __restrict__ t2, const u32* __restrict__ gminu,
                        const u32* __restrict__ wavecnt, const u64* __restrict__ cands,
                        u64* __restrict__ best) {
    const int L = threadIdx.x & 63;
    const int gw = blockIdx.x * (blockDim.x >> 6) + (threadIdx.x >> 6);
    if (gw >= NWAVE_CAP) return;
    u32 cnt = wavecnt[gw];
    if (cnt > WCAP) cnt = WCAP;
    const u64* reg = cands + (size_t)gw * WCAP;
    for (u32 base = 0; base < cnt; base += 64) {
        u32 i = base + L;
        u64 rec = 0; bool pass = false;
        if (i < cnt) {
            rec = reg[i];                                   // coalesced 512 B
            float sb = __uint_as_float((u32)(rec >> 32));
            int q = (int)((rec >> 16) & 0xFFFFu);
            pass = sb < iordf(gminu[q]) + FMARGIN;
        }
        u64 bal = __ballot(pass);
        while (bal) {
            int j = __ffsll((unsigned long long)bal) - 1;
            bal &= bal - 1;
            u64 r2 = __shfl(rec, j, 64);
            int q = (int)((r2 >> 16) & 0xFFFFu);
            int n = (int)(r2 & 0xFFFFu);
            float4 a = *((const float4*)(x  + (size_t)q * F_DIM) + L);
            float4 b = *((const float4*)(Xt + (size_t)n * F_DIM) + L);
            float d = fmaf(a.x, b.x, fmaf(a.y, b.y, fmaf(a.z, b.z, a.w * b.w)));
            #pragma unroll
            for (int st = 32; st > 0; st >>= 1) d += __shfl_xor(d, st, 64);
            if (L == 0) {
                float s = fmaf(-2.f, d, t2[n]);
                u64 p = ((u64)ordf(s) << 32) | (u32)n;
                atomicMin(&best[q], p);
            }
        }
    }
}

// ---------------- gather Y[nearest] ----------------
__global__ void gather_kernel(const float* __restrict__ Y, const u64* __restrict__ best,
                              float* __restrict__ out, int B, int N) {
    int gid = blockIdx.x * blockDim.x + threadIdx.x;
    int total = B * O_DIM;
    if (gid >= total) return;
    int b = gid / O_DIM;
    int o = gid - b * O_DIM;
    u32 n = (u32)(best[b] & 0xFFFFFFFFull);
    if (n >= (u32)N) n = 0;   // defensive
    out[gid] = Y[(size_t)n * O_DIM + o];
}

// ================= fp32 fallback (proven Round-1 path, used if ws too small) =================
#define BM 128
#define BN 128
#define BK 16
#define NSPLIT 64
#define LDA (BM + 4)

__global__ __launch_bounds__(256) void knn_main_fp32(
    const float* __restrict__ Xq, const float* __restrict__ Xt,
    const float* __restrict__ t2, u64* __restrict__ best, int N)
{
    __shared__ float As[BK][LDA];
    __shared__ float Bs[BK][LDA];
    __shared__ u64 red[BM][17];

    const int tid = threadIdx.x;
    const int tx = tid & 15;
    const int ty = tid >> 4;
    const int m0 = blockIdx.y * BM;
    const int CHUNK = (N + NSPLIT - 1) / NSPLIT;
    const int n0c = blockIdx.x * CHUNK;
    const int n1c = min(N, n0c + CHUNK);

    u64 bestv[8];
    #pragma unroll
    for (int i = 0; i < 8; ++i) bestv[i] = ~0ull;

    const int srow = tid >> 2;
    const int scol4 = (tid & 3) * 4;

    for (int nt = n0c; nt < n1c; nt += BN) {
        float accl[8][8];
        #pragma unroll
        for (int i = 0; i < 8; ++i)
            #pragma unroll
            for (int j = 0; j < 8; ++j) accl[i][j] = 0.f;
        for (int k0 = 0; k0 < F_DIM; k0 += BK) {
            #pragma unroll
            for (int h = 0; h < 2; ++h) {
                int row = h * 64 + srow;
                float4 av = *(const float4*)(Xq + (size_t)(m0 + row) * F_DIM + k0 + scol4);
                As[scol4 + 0][row] = av.x; As[scol4 + 1][row] = av.y;
                As[scol4 + 2][row] = av.z; As[scol4 + 3][row] = av.w;
                int n = nt + row;
                float4 bv = make_float4(0.f, 0.f, 0.f, 0.f);
                if (n < n1c) bv = *(const float4*)(Xt + (size_t)n * F_DIM + k0 + scol4);
                Bs[scol4 + 0][row] = bv.x; Bs[scol4 + 1][row] = bv.y;
                Bs[scol4 + 2][row] = bv.z; Bs[scol4 + 3][row] = bv.w;
            }
            __syncthreads();
            #pragma unroll
            for (int k = 0; k < BK; ++k) {
                float4 a0 = *(const float4*)&As[k][ty * 4];
                float4 a1 = *(const float4*)&As[k][64 + ty * 4];
                float4 b0 = *(const float4*)&Bs[k][tx * 4];
                float4 b1 = *(const float4*)&Bs[k][64 + tx * 4];
                float am[8] = {a0.x, a0.y, a0.z, a0.w, a1.x, a1.y, a1.z, a1.w};
                float bn[8] = {b0.x, b0.y, b0.z, b0.w, b1.x, b1.y, b1.z, b1.w};
                #pragma unroll
                for (int i = 0; i < 8; ++i)
                    #pragma unroll
                    for (int j = 0; j < 8; ++j)
                        accl[i][j] = fmaf(am[i], bn[j], accl[i][j]);
            }
            __syncthreads();
        }
        #pragma unroll
        for (int j = 0; j < 8; ++j) {
            int nl = (j < 4) ? (tx * 4 + j) : (64 + tx * 4 + (j - 4));
            int n = nt + nl;
            if (n < n1c) {
                float t2v = t2[n];
                #pragma unroll
                for (int i = 0; i < 8; ++i) {
                    float score = fmaf(-2.f, accl[i][j], t2v);
                    u64 p = ((u64)ordf(score) << 32) | (u32)n;
                    bestv[i] = (p < bestv[i]) ? p : bestv[i];
                }
            }
        }
    }
    #pragma unroll
    for (int i = 0; i < 8; ++i) {
        int ml = (i < 4) ? (ty * 4 + i) : (64 + ty * 4 + (i - 4));
        red[ml][tx] = bestv[i];
    }
    __syncthreads();
    if (tid < BM) {
        u64 b = red[tid][0];
        #pragma unroll
        for (int t = 1; t < 16; ++t) { u64 v = red[tid][t]; b = (v < b) ? v : b; }
        atomicMin(&best[m0 + tid], b);
    }
}

// ================= launch =================
extern "C" void kernel_launch(void* const* d_in, const int* in_sizes, int n_in,
                              void* d_out, int out_size, void* d_ws, size_t ws_size,
                              hipStream_t stream) {
    const float* x  = (const float*)d_in[0];
    const float* Xt = (const float*)d_in[1];
    const float* Yt = (const float*)d_in[2];
    float* out = (float*)d_out;

    const int B = in_sizes[0] / F_DIM;        // 2048
    const int N = in_sizes[1] / F_DIM;        // 50000
    const int NT128 = (N + 127) / 128;        // 391
    const int Npad = NT128 * 128;             // 50048
    const int NT64 = NT128 * 2;               // 782
    const int NT32 = NT64 * 2;                // 1564
    const int MB = B / 256;                   // 8
    const int MT128 = B / 128;                // 16
    const int NCH = 64;                       // 8*64 = 512 blocks = 2/CU (512 thr each)

    char* wsp = (char*)d_ws;
    size_t off = 0;
    auto nxt = [&](size_t bytes) {
        char* p = wsp + off;
        off = (off + bytes + 255) & ~(size_t)255;
        return p;
    };
    float* t2       = (float*)nxt((size_t)Npad * 4);
    u64*   best     = (u64*)  nxt((size_t)B * 8);
    u32*   wavecnt  = (u32*)  nxt((size_t)NWAVE_CAP * 4);
    u32*   gminu    = (u32*)  nxt((size_t)B * 4);
    u64*   cands    = (u64*)  nxt((size_t)NWAVE_CAP * WCAP * 8);
    u16*   xbf      = (u16*)  nxt((size_t)B * F_DIM * 2);
    u16*   xtbf     = (u16*)  nxt((size_t)Npad * F_DIM * 2);
    size_t required = off;

    if (ws_size >= required && B % 256 == 0 && MB * NCH * 8 <= NWAVE_CAP) {
        // 5 launches: convert_x(+init), convert_Xt(+t2), knn_mfma(+gmin atomics), rescore, gather
        convert_tile<<<dim3(MT128, 4), 256, 0, stream>>>(x, xbf, (float*)nullptr, B, 0,
                                                         best, gminu, B);
        convert_tile<<<dim3(NT128, 4), 256, 0, stream>>>(Xt, xtbf, t2, N, 1,
                                                         (u64*)nullptr, (u32*)nullptr, 0);
        knn_mfma<<<dim3(MB * NCH), 512, 0, stream>>>(xbf, xtbf, t2, gminu, wavecnt, cands, NT32, NCH);
        rescore<<<NWAVE_CAP / 4, 256, 0, stream>>>(x, Xt, t2, gminu, wavecnt, cands, best);
    } else {
        init_kernel<<<(B + 255) / 256, 256, 0, stream>>>(best, (u32*)nullptr, B);
        t2_kernel<<<(N + 3) / 4, 256, 0, stream>>>(Xt, t2, N, N);
        dim3 grid(NSPLIT, B / BM);
        knn_main_fp32<<<grid, 256, 0, stream>>>(x, Xt, t2, best, N);
    }

    int total = B * O_DIM;
    gather_kernel<<<(total + 255) / 256, 256, 0, stream>>>(Yt, best, out, B, N);
}

// Round 9
// 214.927 us; speedup vs baseline: 1.1140x; 1.0900x over previous
//
#include <hip/hip_runtime.h>
#include <stdint.h>

typedef unsigned short u16;
typedef unsigned int   u32;
typedef unsigned long long u64;

#define F_DIM 256
#define O_DIM 24
#define MARGIN  3.0f      // capture margin (>= 2E bf16-vs-fp32 score bound; validated R2-R13)
#define FMARGIN 3.0f      // rescore global filter margin (same bound)
#define WCAP 512          // candidate slots per capture-wave (8 B each)
#define NWAVE_CAP 4096    // 8 mb * 64 chunks * 8 waves

#define AS1 __attribute__((address_space(1)))
#define AS3 __attribute__((address_space(3)))

typedef __bf16 bf16x8 __attribute__((ext_vector_type(8)));
typedef float  f32x4  __attribute__((ext_vector_type(4)));

__device__ __forceinline__ u32 ordf(float s) {
    u32 b = __float_as_uint(s);
    return (b & 0x80000000u) ? ~b : (b | 0x80000000u);
}
__device__ __forceinline__ float iordf(u32 e) {   // inverse of ordf
    return __uint_as_float((e & 0x80000000u) ? (e ^ 0x80000000u) : ~e);
}
__device__ __forceinline__ u16 f2bf(float f) {   // round-to-nearest-even
    u32 u = __float_as_uint(f);
    u32 r = (u + 0x7FFFu + ((u >> 16) & 1u)) >> 16;
    return (u16)r;
}

// ---------------- init (fallback path only) ----------------
__global__ void init_kernel(u64* best, u32* gminu, int B) {
    int i = blockIdx.x * blockDim.x + threadIdx.x;
    if (i < B) { best[i] = ~0ull; if (gminu) gminu[i] = ordf(1e30f); }
}

// ---------------- t2 (fallback path only) ----------------
__global__ void t2_kernel(const float* __restrict__ X, float* __restrict__ t2,
                          int N, int Npad) {
    int tid = threadIdx.x;
    int row = blockIdx.x * 4 + (tid >> 6);
    int lane = tid & 63;
    if (row >= Npad) return;
    if (row >= N) { if (lane == 0) t2[row] = 1e30f; return; }
    float4 v = ((const float4*)(X + (size_t)row * F_DIM))[lane];
    float s = v.x * v.x + v.y * v.y + v.z * v.z + v.w * v.w;
    #pragma unroll
    for (int off = 32; off > 0; off >>= 1) s += __shfl_down(s, off, 64);
    if (lane == 0) t2[row] = s;
}

// ---------------- merged converter: x-tiles and Xt-tiles in ONE launch ----------------
// blockIdx.x < mt128 -> x (fused best/gminu init); else Xt (fused t2).
__global__ __launch_bounds__(256) void convert_dual(
        const float* __restrict__ x, u16* __restrict__ xbf, int B,
        const float* __restrict__ Xt, u16* __restrict__ xtbf, float* __restrict__ t2out, int N,
        int mt128, u64* best, u32* gminu) {
    __shared__ u16 tl[8192];   // 16 KB
    const int tid = threadIdx.x;
    const int tg = blockIdx.x, p = blockIdx.y;
    const bool isX = tg < mt128;
    const int t = isX ? tg : tg - mt128;
    const float* src = isX ? x : Xt;
    u16* dst = isX ? xbf : xtbf;
    const int nrows = isX ? B : N;
    if (isX) {
        int id = (p * mt128 + t) * 256 + tid;
        if (id < B) { best[id] = ~0ull; gminu[id] = ordf(1e30f); }
    }
    const int w = tid >> 6, L = tid & 63;
    const int col = L * 4;
    const int ks = col >> 5, j = col & 7, lhi = ((col >> 3) & 3) << 4;
    #pragma unroll
    for (int i = 0; i < 8; ++i) {
        int rloc = i * 4 + w;
        int grow = t * 128 + p * 32 + rloc;
        float4 v = make_float4(0.f, 0.f, 0.f, 0.f);
        if (grow < nrows) v = *(const float4*)(src + (size_t)grow * F_DIM + col);
        if (!isX) {
            float s = v.x * v.x + v.y * v.y + v.z * v.z + v.w * v.w;
            #pragma unroll
            for (int off = 32; off > 0; off >>= 1) s += __shfl_down(s, off, 64);
            if (L == 0) t2out[grow] = (grow < nrows) ? s : 1e30f;
        }
        u16* q = &tl[ks * 1024 + (rloc >> 4) * 512 + (((rloc & 15) | lhi)) * 8 + j];
        q[0] = f2bf(v.x); q[1] = f2bf(v.y); q[2] = f2bf(v.z); q[3] = f2bf(v.w);
    }
    __syncthreads();
    const uint4* s4 = (const uint4*)tl;
    uint4* d4 = (uint4*)(dst + (size_t)t * 32768);
    #pragma unroll
    for (int v = 0; v < 4; ++v) {
        int lin = v * 256 + tid;
        int ksc = lin >> 7, subl = (lin >> 6) & 1, lane = lin & 63;
        d4[(ksc * 8 + 2 * p + subl) * 64 + lane] = s4[lin];
    }
}

// ---------------- main: R9 = R8 body, 2 half-tiles per barrier + t2-before-STAGE ----------------
// R8 confirmed the R5 body (130 us, traffic clean). NEW finding: in R5/R8 program order
// (STAGE -> t2 load -> MFMA), the compiler's vmcnt wait for t2v forces an in-order
// drain of the JUST-ISSUED prefetch every iteration -- the double-buffer never overlapped.
// R9: (a) load t2v BEFORE issuing STAGE so its wait covers only old, landed ops and the
// prefetch stays in flight until the end-of-iter barrier; (b) process TWO half-tiles per
// barrier (4 x 16 KB ring, prefetch next pair during current pair's compute): barriers
// 24 -> 12, compute window per stage doubled. No inline-asm waits (R7 lesson: the
// compiler schedules better than sched_barrier(0) pinning; counted vmcnt was polluted
// by candidate stores). Registers ~+6 vs R8, still well under the 128 cap.
__global__ __launch_bounds__(512, 2) void knn_mfma(
    const u16* __restrict__ xbf, const u16* __restrict__ xtbf,
    const float* __restrict__ t2, u32* __restrict__ gminu,
    u32* __restrict__ wavecnt, u64* __restrict__ cands,
    int ntiles /*32-col tiles*/, int nch)
{
    __shared__ u16 sB[4][8192];   // 4 x 16 KB ring (32-col half-tiles, used in pairs)

    const int tid = threadIdx.x;
    const int L = tid & 63, w = tid >> 6;   // 8 waves
    const int lid = blockIdx.x;
    const int mbcnt = (int)(gridDim.x) / nch;
    int mb, chunk;
    if (nch == 64 && mbcnt == 8) {
        const int xg = lid & 7, slot = lid >> 3;
        chunk = xg * 8 + (slot >> 3);       // 8 chunks per XCD (round-robin or contiguous)
        mb = slot & 7;
    } else {
        mb = lid % mbcnt;                   // legacy linearization
        chunk = lid / mbcnt;
    }
    const int gwave = (mb * 64 + chunk) * 8 + w;
    const int t0 = (int)(((long long)chunk * ntiles) / nch);
    const int t1 = (int)(((long long)(chunk + 1) * ntiles) / nch);

    // nt is a 32-col half-tile: nt64 = nt>>1, half = nt&1
    #define TBASE_U32(nt) ((const AS1 u32*)xtbf + (size_t)((nt) >> 2) * 16384 \
                           + (size_t)(((nt) >> 1) & 1) * 1024 + (size_t)((nt) & 1) * 512)

    // ---- stage one 16 KB half-tile (async, 2 x 512 threads x 16 B) ----
    #define STAGE(buf, nt) do {                                                        \
        const AS1 u32* gp_ = TBASE_U32(nt);                                            \
        AS3 u32* lb_ = (AS3 u32*)&sB[buf][0];                                          \
        _Pragma("unroll")                                                              \
        for (int j = 0; j < 2; ++j) {                                                  \
            const int unit = j * 8 + w;                                                \
            __builtin_amdgcn_global_load_lds(                                          \
                gp_ + (size_t)(unit >> 1) * 2048 + (size_t)(unit & 1) * 256            \
                    + (size_t)L * 4,                                                   \
                lb_ + unit * 256, 16, 0, 0);                                           \
        }                                                                              \
    } while (0)

    STAGE(0, t0);
    if (t0 + 1 < t1) STAGE(1, t0 + 1);

    // ---- A fragments in registers: wave w owns rows mb*256 + w*32 .. +31 ----
    bf16x8 areg[16];
    {
        const int t128 = mb * 2 + (w >> 2);
        const u16* base = xbf + (size_t)t128 * 32768 + (size_t)(w & 3) * 1024 + (size_t)L * 8;
        #pragma unroll
        for (int ks = 0; ks < 8; ++ks)
            #pragma unroll
            for (int i = 0; i < 2; ++i)
                areg[ks * 2 + i] = *(const bf16x8*)(base + ks * 4096 + i * 512);
    }

    float rowmin_reg[2][4];
    #pragma unroll
    for (int i = 0; i < 2; ++i)
        #pragma unroll
        for (int r = 0; r < 4; ++r) rowmin_reg[i][r] = 1e30f;

    u32 wcount = 0;
    u64* const wreg = cands + (size_t)gwave * WCAP;

    __syncthreads();   // first pair staged

    // process one 32-col half-tile from LDS buffer `buf`
    auto process = [&](int nt, int buf, const float* t2v) {
        f32x4 acc[2][2];
        #pragma unroll
        for (int i = 0; i < 2; ++i)
            #pragma unroll
            for (int c = 0; c < 2; ++c)
                #pragma unroll
                for (int r = 0; r < 4; ++r) acc[i][c][r] = 0.f;

        #pragma unroll
        for (int ks = 0; ks < 8; ++ks) {
            bf16x8 bc[2];
            #pragma unroll
            for (int c = 0; c < 2; ++c)
                bc[c] = *(const bf16x8*)&sB[buf][ks * 1024 + c * 512 + L * 8];
            #pragma unroll
            for (int i = 0; i < 2; ++i)
                #pragma unroll
                for (int c = 0; c < 2; ++c)
                    acc[i][c] = __builtin_amdgcn_mfma_f32_16x16x32_bf16(areg[ks * 2 + i], bc[c], acc[i][c], 0, 0, 0);
        }

        // ---- epilogue ----
        const int colb = nt * 32 + (L & 15);
        float r4[2][4];
        #pragma unroll
        for (int i = 0; i < 2; ++i) {
            #pragma unroll
            for (int r = 0; r < 4; ++r) r4[i][r] = 1e30f;
            #pragma unroll
            for (int c = 0; c < 2; ++c)
                #pragma unroll
                for (int r = 0; r < 4; ++r)
                    r4[i][r] = fminf(r4[i][r], fmaf(-2.f, acc[i][c][r], t2v[c]));
        }

        // threshold base (subset-min of the row's bf16 scores: safe with MARGIN >= 2E)
        float thb[2][4];
        if (nt == t0) {
            // seed: butterfly tile-t0 row-min FIRST so t0 capture doesn't flood
            #pragma unroll
            for (int i = 0; i < 2; ++i)
                #pragma unroll
                for (int r = 0; r < 4; ++r) rowmin_reg[i][r] = r4[i][r];
            #pragma unroll
            for (int st = 1; st <= 8; st <<= 1)
                #pragma unroll
                for (int i = 0; i < 2; ++i)
                    #pragma unroll
                    for (int r = 0; r < 4; ++r)
                        rowmin_reg[i][r] = fminf(rowmin_reg[i][r], __shfl_xor(rowmin_reg[i][r], st, 64));
            #pragma unroll
            for (int i = 0; i < 2; ++i)
                #pragma unroll
                for (int r = 0; r < 4; ++r) thb[i][r] = rowmin_reg[i][r];
        } else {
            #pragma unroll
            for (int i = 0; i < 2; ++i)
                #pragma unroll
                for (int r = 0; r < 4; ++r) thb[i][r] = fminf(rowmin_reg[i][r], r4[i][r]);
        }

        bool anyhit = false;
        #pragma unroll
        for (int i = 0; i < 2; ++i)
            #pragma unroll
            for (int r = 0; r < 4; ++r)
                anyhit = anyhit || (r4[i][r] < thb[i][r] + MARGIN);

        if (__any(anyhit)) {
            u32 cnt = 0;
            #pragma unroll
            for (int i = 0; i < 2; ++i)
                #pragma unroll
                for (int r = 0; r < 4; ++r) {
                    float th = thb[i][r] + MARGIN;
                    if (r4[i][r] < th) {
                        #pragma unroll
                        for (int c = 0; c < 2; ++c)
                            cnt += (fmaf(-2.f, acc[i][c][r], t2v[c]) < th) ? 1u : 0u;
                    }
                }
            u32 pre = cnt;
            #pragma unroll
            for (int d = 1; d < 64; d <<= 1) {
                u32 v = __shfl_up(pre, d, 64);
                if (L >= d) pre += v;
            }
            u32 total = __shfl(pre, 63, 64);
            u32 woff = wcount + pre - cnt;
            #pragma unroll
            for (int i = 0; i < 2; ++i)
                #pragma unroll
                for (int r = 0; r < 4; ++r) {
                    float th = thb[i][r] + MARGIN;
                    if (r4[i][r] < th) {
                        const int q = mb * 256 + w * 32 + i * 16 + (L >> 4) * 4 + r;
                        #pragma unroll
                        for (int c = 0; c < 2; ++c) {
                            float s = fmaf(-2.f, acc[i][c][r], t2v[c]);
                            if (s < th) {
                                if (woff < WCAP)
                                    wreg[woff] = ((u64)__float_as_uint(s) << 32)
                                               | (u64)(((u32)q << 16) | (u32)(colb + c * 16));
                                woff++;
                            }
                        }
                    }
                }
            wcount += total;
        }

        // fold per-lane; full 16-lane butterfly only every 4th half-tile
        #pragma unroll
        for (int i = 0; i < 2; ++i)
            #pragma unroll
            for (int r = 0; r < 4; ++r)
                rowmin_reg[i][r] = fminf(rowmin_reg[i][r], r4[i][r]);
        if (((nt - t0) & 3) == 3) {
            #pragma unroll
            for (int st = 1; st <= 8; st <<= 1)
                #pragma unroll
                for (int i = 0; i < 2; ++i)
                    #pragma unroll
                    for (int r = 0; r < 4; ++r)
                        rowmin_reg[i][r] = fminf(rowmin_reg[i][r], __shfl_xor(rowmin_reg[i][r], st, 64));
        }
    };

    for (int nt = t0; nt < t1; nt += 2) {
        const int cb = ((((nt - t0) >> 1) & 1) << 1);   // current buffer base (0 or 2)
        const bool has2 = (nt + 1 < t1);

        // t2 loads FIRST: their wait must not force a drain of the fresh prefetch
        float t2a[2], t2b[2];
        #pragma unroll
        for (int c = 0; c < 2; ++c) t2a[c] = t2[nt * 32 + (L & 15) + c * 16];
        if (has2)
            #pragma unroll
            for (int c = 0; c < 2; ++c) t2b[c] = t2[(nt + 1) * 32 + (L & 15) + c * 16];

        // prefetch next pair into the other buffer pair (consumed after next barrier)
        if (nt + 2 < t1) STAGE(cb ^ 2, nt + 2);
        if (nt + 3 < t1) STAGE((cb ^ 2) + 1, nt + 3);

        process(nt, cb, t2a);
        if (has2) process(nt + 1, cb + 1, t2b);

        __syncthreads();   // drains pair prefetch + protects buffer reuse (1 barrier / 2 tiles)
    }

    // ---- final: exact chunk row-min -> global gmin atomics + candidate count ----
    #pragma unroll
    for (int st = 1; st <= 8; st <<= 1)
        #pragma unroll
        for (int i = 0; i < 2; ++i)
            #pragma unroll
            for (int r = 0; r < 4; ++r)
                rowmin_reg[i][r] = fminf(rowmin_reg[i][r], __shfl_xor(rowmin_reg[i][r], st, 64));
    if ((L & 15) == 0) {
        #pragma unroll
        for (int i = 0; i < 2; ++i)
            #pragma unroll
            for (int r = 0; r < 4; ++r) {
                int q = mb * 256 + w * 32 + i * 16 + (L >> 4) * 4 + r;
                atomicMin(&gminu[q], ordf(rowmin_reg[i][r]));
            }
    }
    if (L == 0) wavecnt[gwave] = (wcount < WCAP) ? wcount : WCAP;
    #undef STAGE
    #undef TBASE_U32
}

// ---------------- filtered exact fp32 rescore: ballot-compacted, wave-cooperative ----------------
__global__ void rescore(const float* __restrict__ x, const float* __restrict__ Xt,
                        const float* __restrict__ t2, const u32* __restrict__ gminu,
                        const u32* __restrict__ wavecnt, const u64* __restrict__ cands,
                        u64* __restrict__ best) {
    const int L = threadIdx.x & 63;
    const int gw = blockIdx.x * (blockDim.x >> 6) + (threadIdx.x >> 6);
    if (gw >= NWAVE_CAP) return;
    u32 cnt = wavecnt[gw];
    if (cnt > WCAP) cnt = WCAP;
    const u64* reg = cands + (size_t)gw * WCAP;
    for (u32 base = 0; base < cnt; base += 64) {
        u32 i = base + L;
        u64 rec = 0; bool pass = false;
        if (i < cnt) {
            rec = reg[i];                                   // coalesced 512 B
            float sb = __uint_as_float((u32)(rec >> 32));
            int q = (int)((rec >> 16) & 0xFFFFu);
            pass = sb < iordf(gminu[q]) + FMARGIN;
        }
        u64 bal = __ballot(pass);
        while (bal) {
            int j = __ffsll((unsigned long long)bal) - 1;
            bal &= bal - 1;
            u64 r2 = __shfl(rec, j, 64);
            int q = (int)((r2 >> 16) & 0xFFFFu);
            int n = (int)(r2 & 0xFFFFu);
            float4 a = *((const float4*)(x  + (size_t)q * F_DIM) + L);
            float4 b = *((const float4*)(Xt + (size_t)n * F_DIM) + L);
            float d = fmaf(a.x, b.x, fmaf(a.y, b.y, fmaf(a.z, b.z, a.w * b.w)));
            #pragma unroll
            for (int st = 32; st > 0; st >>= 1) d += __shfl_xor(d, st, 64);
            if (L == 0) {
                float s = fmaf(-2.f, d, t2[n]);
                u64 p = ((u64)ordf(s) << 32) | (u32)n;
                atomicMin(&best[q], p);
            }
        }
    }
}

// ---------------- gather Y[nearest] ----------------
__global__ void gather_kernel(const float* __restrict__ Y, const u64* __restrict__ best,
                              float* __restrict__ out, int B, int N) {
    int gid = blockIdx.x * blockDim.x + threadIdx.x;
    int total = B * O_DIM;
    if (gid >= total) return;
    int b = gid / O_DIM;
    int o = gid - b * O_DIM;
    u32 n = (u32)(best[b] & 0xFFFFFFFFull);
    if (n >= (u32)N) n = 0;   // defensive
    out[gid] = Y[(size_t)n * O_DIM + o];
}

// ================= fp32 fallback (proven Round-1 path, used if ws too small) =================
#define BM 128
#define BN 128
#define BK 16
#define NSPLIT 64
#define LDA (BM + 4)

__global__ __launch_bounds__(256) void knn_main_fp32(
    const float* __restrict__ Xq, const float* __restrict__ Xt,
    const float* __restrict__ t2, u64* __restrict__ best, int N)
{
    __shared__ float As[BK][LDA];
    __shared__ float Bs[BK][LDA];
    __shared__ u64 red[BM][17];

    const int tid = threadIdx.x;
    const int tx = tid & 15;
    const int ty = tid >> 4;
    const int m0 = blockIdx.y * BM;
    const int CHUNK = (N + NSPLIT - 1) / NSPLIT;
    const int n0c = blockIdx.x * CHUNK;
    const int n1c = min(N, n0c + CHUNK);

    u64 bestv[8];
    #pragma unroll
    for (int i = 0; i < 8; ++i) bestv[i] = ~0ull;

    const int srow = tid >> 2;
    const int scol4 = (tid & 3) * 4;

    for (int nt = n0c; nt < n1c; nt += BN) {
        float accl[8][8];
        #pragma unroll
        for (int i = 0; i < 8; ++i)
            #pragma unroll
            for (int j = 0; j < 8; ++j) accl[i][j] = 0.f;
        for (int k0 = 0; k0 < F_DIM; k0 += BK) {
            #pragma unroll
            for (int h = 0; h < 2; ++h) {
                int row = h * 64 + srow;
                float4 av = *(const float4*)(Xq + (size_t)(m0 + row) * F_DIM + k0 + scol4);
                As[scol4 + 0][row] = av.x; As[scol4 + 1][row] = av.y;
                As[scol4 + 2][row] = av.z; As[scol4 + 3][row] = av.w;
                int n = nt + row;
                float4 bv = make_float4(0.f, 0.f, 0.f, 0.f);
                if (n < n1c) bv = *(const float4*)(Xt + (size_t)n * F_DIM + k0 + scol4);
                Bs[scol4 + 0][row] = bv.x; Bs[scol4 + 1][row] = bv.y;
                Bs[scol4 + 2][row] = bv.z; Bs[scol4 + 3][row] = bv.w;
            }
            __syncthreads();
            #pragma unroll
            for (int k = 0; k < BK; ++k) {
                float4 a0 = *(const float4*)&As[k][ty * 4];
                float4 a1 = *(const float4*)&As[k][64 + ty * 4];
                float4 b0 = *(const float4*)&Bs[k][tx * 4];
                float4 b1 = *(const float4*)&Bs[k][64 + tx * 4];
                float am[8] = {a0.x, a0.y, a0.z, a0.w, a1.x, a1.y, a1.z, a1.w};
                float bn[8] = {b0.x, b0.y, b0.z, b0.w, b1.x, b1.y, b1.z, b1.w};
                #pragma unroll
                for (int i = 0; i < 8; ++i)
                    #pragma unroll
                    for (int j = 0; j < 8; ++j)
                        accl[i][j] = fmaf(am[i], bn[j], accl[i][j]);
            }
            __syncthreads();
        }
        #pragma unroll
        for (int j = 0; j < 8; ++j) {
            int nl = (j < 4) ? (tx * 4 + j) : (64 + tx * 4 + (j - 4));
            int n = nt + nl;
            if (n < n1c) {
                float t2v = t2[n];
                #pragma unroll
                for (int i = 0; i < 8; ++i) {
                    float score = fmaf(-2.f, accl[i][j], t2v);
                    u64 p = ((u64)ordf(score) << 32) | (u32)n;
                    bestv[i] = (p < bestv[i]) ? p : bestv[i];
                }
            }
        }
    }
    #pragma unroll
    for (int i = 0; i < 8; ++i) {
        int ml = (i < 4) ? (ty * 4 + i) : (64 + ty * 4 + (i - 4));
        red[ml][tx] = bestv[i];
    }
    __syncthreads();
    if (tid < BM) {
        u64 b = red[tid][0];
        #pragma unroll
        for (int t = 1; t < 16; ++t) { u64 v = red[tid][t]; b = (v < b) ? v : b; }
        atomicMin(&best[m0 + tid], b);
    }
}

// ================= launch =================
extern "C" void kernel_launch(void* const* d_in, const int* in_sizes, int n_in,
                              void* d_out, int out_size, void* d_ws, size_t ws_size,
                              hipStream_t stream) {
    const float* x  = (const float*)d_in[0];
    const float* Xt = (const float*)d_in[1];
    const float* Yt = (const float*)d_in[2];
    float* out = (float*)d_out;

    const int B = in_sizes[0] / F_DIM;        // 2048
    const int N = in_sizes[1] / F_DIM;        // 50000
    const int NT128 = (N + 127) / 128;        // 391
    const int Npad = NT128 * 128;             // 50048
    const int NT64 = NT128 * 2;               // 782
    const int NT32 = NT64 * 2;                // 1564
    const int MB = B / 256;                   // 8
    const int MT128 = B / 128;                // 16
    const int NCH = 64;                       // 8*64 = 512 blocks = 2/CU (512 thr each)

    char* wsp = (char*)d_ws;
    size_t off = 0;
    auto nxt = [&](size_t bytes) {
        char* p = wsp + off;
        off = (off + bytes + 255) & ~(size_t)255;
        return p;
    };
    float* t2       = (float*)nxt((size_t)Npad * 4);
    u64*   best     = (u64*)  nxt((size_t)B * 8);
    u32*   wavecnt  = (u32*)  nxt((size_t)NWAVE_CAP * 4);
    u32*   gminu    = (u32*)  nxt((size_t)B * 4);
    u64*   cands    = (u64*)  nxt((size_t)NWAVE_CAP * WCAP * 8);
    u16*   xbf      = (u16*)  nxt((size_t)B * F_DIM * 2);
    u16*   xtbf     = (u16*)  nxt((size_t)Npad * F_DIM * 2);
    size_t required = off;

    if (ws_size >= required && B % 256 == 0 && MB * NCH * 8 <= NWAVE_CAP) {
        // 4 launches: convert_dual(x+Xt, fused init+t2), knn_mfma(+gmin atomics), rescore, gather
        convert_dual<<<dim3(MT128 + NT128, 4), 256, 0, stream>>>(
            x, xbf, B, Xt, xtbf, t2, N, MT128, best, gminu);
        knn_mfma<<<dim3(MB * NCH), 512, 0, stream>>>(xbf, xtbf, t2, gminu, wavecnt, cands, NT32, NCH);
        rescore<<<NWAVE_CAP / 4, 256, 0, stream>>>(x, Xt, t2, gminu, wavecnt, cands, best);
    } else {
        init_kernel<<<(B + 255) / 256, 256, 0, stream>>>(best, (u32*)nullptr, B);
        t2_kernel<<<(N + 3) / 4, 256, 0, stream>>>(Xt, t2, N, N);
        dim3 grid(NSPLIT, B / BM);
        knn_main_fp32<<<grid, 256, 0, stream>>>(x, Xt, t2, best, N);
    }

    int total = B * O_DIM;
    gather_kernel<<<(total + 255) / 256, 256, 0, stream>>>(Yt, best, out, B, N);
}

// Round 10
// 210.526 us; speedup vs baseline: 1.1373x; 1.0209x over previous
//
#include <hip/hip_runtime.h>
#include <stdint.h>

typedef unsigned short u16;
typedef unsigned int   u32;
typedef unsigned long long u64;

#define F_DIM 256
#define O_DIM 24
#define MARGIN  3.0f      // capture margin (>= 2E bf16-vs-fp32 score bound; validated R2-R13)
#define FMARGIN 3.0f      // rescore global filter margin (same bound)
#define WCAP 512          // candidate slots per capture-wave (8 B each)
#define NWAVE_CAP 4096    // 8 mb * 64 chunks * 8 waves

#define AS1 __attribute__((address_space(1)))
#define AS3 __attribute__((address_space(3)))

typedef __bf16 bf16x8 __attribute__((ext_vector_type(8)));
typedef float  f32x4  __attribute__((ext_vector_type(4)));

__device__ __forceinline__ u32 ordf(float s) {
    u32 b = __float_as_uint(s);
    return (b & 0x80000000u) ? ~b : (b | 0x80000000u);
}
__device__ __forceinline__ float iordf(u32 e) {   // inverse of ordf
    return __uint_as_float((e & 0x80000000u) ? (e ^ 0x80000000u) : ~e);
}
__device__ __forceinline__ u16 f2bf(float f) {   // round-to-nearest-even
    u32 u = __float_as_uint(f);
    u32 r = (u + 0x7FFFu + ((u >> 16) & 1u)) >> 16;
    return (u16)r;
}

// ---------------- init (fallback path only) ----------------
__global__ void init_kernel(u64* best, u32* gminu, int B) {
    int i = blockIdx.x * blockDim.x + threadIdx.x;
    if (i < B) { best[i] = ~0ull; if (gminu) gminu[i] = ordf(1e30f); }
}

// ---------------- t2 (fallback path only) ----------------
__global__ void t2_kernel(const float* __restrict__ X, float* __restrict__ t2,
                          int N, int Npad) {
    int tid = threadIdx.x;
    int row = blockIdx.x * 4 + (tid >> 6);
    int lane = tid & 63;
    if (row >= Npad) return;
    if (row >= N) { if (lane == 0) t2[row] = 1e30f; return; }
    float4 v = ((const float4*)(X + (size_t)row * F_DIM))[lane];
    float s = v.x * v.x + v.y * v.y + v.z * v.z + v.w * v.w;
    #pragma unroll
    for (int off = 32; off > 0; off >>= 1) s += __shfl_down(s, off, 64);
    if (lane == 0) t2[row] = s;
}

// ---------------- merged converter: x-tiles and Xt-tiles in ONE launch ----------------
// blockIdx.x < mt128 -> x (fused best/gminu init); else Xt (fused t2).
__global__ __launch_bounds__(256) void convert_dual(
        const float* __restrict__ x, u16* __restrict__ xbf, int B,
        const float* __restrict__ Xt, u16* __restrict__ xtbf, float* __restrict__ t2out, int N,
        int mt128, u64* best, u32* gminu) {
    __shared__ u16 tl[8192];   // 16 KB
    const int tid = threadIdx.x;
    const int tg = blockIdx.x, p = blockIdx.y;
    const bool isX = tg < mt128;
    const int t = isX ? tg : tg - mt128;
    const float* src = isX ? x : Xt;
    u16* dst = isX ? xbf : xtbf;
    const int nrows = isX ? B : N;
    if (isX) {
        int id = (p * mt128 + t) * 256 + tid;
        if (id < B) { best[id] = ~0ull; gminu[id] = ordf(1e30f); }
    }
    const int w = tid >> 6, L = tid & 63;
    const int col = L * 4;
    const int ks = col >> 5, j = col & 7, lhi = ((col >> 3) & 3) << 4;
    #pragma unroll
    for (int i = 0; i < 8; ++i) {
        int rloc = i * 4 + w;
        int grow = t * 128 + p * 32 + rloc;
        float4 v = make_float4(0.f, 0.f, 0.f, 0.f);
        if (grow < nrows) v = *(const float4*)(src + (size_t)grow * F_DIM + col);
        if (!isX) {
            float s = v.x * v.x + v.y * v.y + v.z * v.z + v.w * v.w;
            #pragma unroll
            for (int off = 32; off > 0; off >>= 1) s += __shfl_down(s, off, 64);
            if (L == 0) t2out[grow] = (grow < nrows) ? s : 1e30f;
        }
        u16* q = &tl[ks * 1024 + (rloc >> 4) * 512 + (((rloc & 15) | lhi)) * 8 + j];
        q[0] = f2bf(v.x); q[1] = f2bf(v.y); q[2] = f2bf(v.z); q[3] = f2bf(v.w);
    }
    __syncthreads();
    const uint4* s4 = (const uint4*)tl;
    uint4* d4 = (uint4*)(dst + (size_t)t * 32768);
    #pragma unroll
    for (int v = 0; v < 4; ++v) {
        int lin = v * 256 + tid;
        int ksc = lin >> 7, subl = (lin >> 6) & 1, lane = lin & 63;
        d4[(ksc * 8 + 2 * p + subl) * 64 + lane] = s4[lin];
    }
}

// ---------------- main: R10 = R9 pipeline + ONE epilogue per 64-col pair ----------------
// R9 confirmed (113 us): t2-before-STAGE made the prefetch overlap real; VALU is now
// the dominant busy pipe (37%, ~8.2K cyc/SIMD/pair vs MFMA 5K). R10 cuts VALU work:
// the two half-tiles of a pair accumulate into ONE acc[2][4] and the whole epilogue
// (thb/anyhit/capture-scan/rowmin/t2-addressing/loop control) runs once per 64 cols
// instead of once per 32 -- halving per-score bookkeeping overhead. Odd tail: the
// missing half-tile gets t2v[2..3]=1e30f so its columns' scores are +inf (never min,
// never captured); the stale LDS it reads is inert. thb stays a subset-min of real
// columns -> capture-threshold correctness unchanged. acc 16->32 VGPR: expect ~100-116
// total, under the (512,2) 128-reg cap. Spill tell-tale = FETCH/WRITE blow-up (R4).
__global__ __launch_bounds__(512, 2) void knn_mfma(
    const u16* __restrict__ xbf, const u16* __restrict__ xtbf,
    const float* __restrict__ t2, u32* __restrict__ gminu,
    u32* __restrict__ wavecnt, u64* __restrict__ cands,
    int ntiles /*32-col tiles*/, int nch)
{
    __shared__ u16 sB[4][8192];   // 4 x 16 KB ring (32-col half-tiles, used in pairs)

    const int tid = threadIdx.x;
    const int L = tid & 63, w = tid >> 6;   // 8 waves
    const int lid = blockIdx.x;
    const int mbcnt = (int)(gridDim.x) / nch;
    int mb, chunk;
    if (nch == 64 && mbcnt == 8) {
        const int xg = lid & 7, slot = lid >> 3;
        chunk = xg * 8 + (slot >> 3);       // 8 chunks per XCD (round-robin or contiguous)
        mb = slot & 7;
    } else {
        mb = lid % mbcnt;                   // legacy linearization
        chunk = lid / mbcnt;
    }
    const int gwave = (mb * 64 + chunk) * 8 + w;
    const int t0 = (int)(((long long)chunk * ntiles) / nch);
    const int t1 = (int)(((long long)(chunk + 1) * ntiles) / nch);

    // nt is a 32-col half-tile: nt64 = nt>>1, half = nt&1
    #define TBASE_U32(nt) ((const AS1 u32*)xtbf + (size_t)((nt) >> 2) * 16384 \
                           + (size_t)(((nt) >> 1) & 1) * 1024 + (size_t)((nt) & 1) * 512)

    // ---- stage one 16 KB half-tile (async, 2 x 512 threads x 16 B) ----
    #define STAGE(buf, nt) do {                                                        \
        const AS1 u32* gp_ = TBASE_U32(nt);                                            \
        AS3 u32* lb_ = (AS3 u32*)&sB[buf][0];                                          \
        _Pragma("unroll")                                                              \
        for (int j = 0; j < 2; ++j) {                                                  \
            const int unit = j * 8 + w;                                                \
            __builtin_amdgcn_global_load_lds(                                          \
                gp_ + (size_t)(unit >> 1) * 2048 + (size_t)(unit & 1) * 256            \
                    + (size_t)L * 4,                                                   \
                lb_ + unit * 256, 16, 0, 0);                                           \
        }                                                                              \
    } while (0)

    STAGE(0, t0);
    if (t0 + 1 < t1) STAGE(1, t0 + 1);

    // ---- A fragments in registers: wave w owns rows mb*256 + w*32 .. +31 ----
    bf16x8 areg[16];
    {
        const int t128 = mb * 2 + (w >> 2);
        const u16* base = xbf + (size_t)t128 * 32768 + (size_t)(w & 3) * 1024 + (size_t)L * 8;
        #pragma unroll
        for (int ks = 0; ks < 8; ++ks)
            #pragma unroll
            for (int i = 0; i < 2; ++i)
                areg[ks * 2 + i] = *(const bf16x8*)(base + ks * 4096 + i * 512);
    }

    float rowmin_reg[2][4];
    #pragma unroll
    for (int i = 0; i < 2; ++i)
        #pragma unroll
        for (int r = 0; r < 4; ++r) rowmin_reg[i][r] = 1e30f;

    u32 wcount = 0;
    u64* const wreg = cands + (size_t)gwave * WCAP;

    __syncthreads();   // first pair staged

    for (int nt = t0; nt < t1; nt += 2) {
        const int cb = ((((nt - t0) >> 1) & 1) << 1);   // current buffer base (0 or 2)
        const bool has2 = (nt + 1 < t1);

        // t2 loads FIRST (R9): their wait must not drain the fresh prefetch.
        // Odd tail: t2v[2..3] = +inf -> those columns inert (never min / never captured).
        float t2v[4];
        #pragma unroll
        for (int c = 0; c < 2; ++c) t2v[c] = t2[nt * 32 + (L & 15) + c * 16];
        if (has2) {
            #pragma unroll
            for (int c = 2; c < 4; ++c) t2v[c] = t2[(nt + 1) * 32 + (L & 15) + (c - 2) * 16];
        } else {
            t2v[2] = 1e30f; t2v[3] = 1e30f;
        }

        // prefetch next pair into the other buffer pair (consumed after next barrier)
        if (nt + 2 < t1) STAGE(cb ^ 2, nt + 2);
        if (nt + 3 < t1) STAGE((cb ^ 2) + 1, nt + 3);

        // ---- MFMA over BOTH half-tiles into one acc[2][4] ----
        f32x4 acc[2][4];
        #pragma unroll
        for (int i = 0; i < 2; ++i)
            #pragma unroll
            for (int c = 0; c < 4; ++c)
                #pragma unroll
                for (int r = 0; r < 4; ++r) acc[i][c][r] = 0.f;

        #pragma unroll
        for (int ks = 0; ks < 8; ++ks) {
            bf16x8 bc[4];
            #pragma unroll
            for (int c = 0; c < 4; ++c)
                bc[c] = *(const bf16x8*)&sB[cb + (c >> 1)][ks * 1024 + (c & 1) * 512 + L * 8];
            #pragma unroll
            for (int i = 0; i < 2; ++i)
                #pragma unroll
                for (int c = 0; c < 4; ++c)
                    acc[i][c] = __builtin_amdgcn_mfma_f32_16x16x32_bf16(areg[ks * 2 + i], bc[c], acc[i][c], 0, 0, 0);
        }

        // ---- ONE epilogue per 64 cols ----
        const int colb = nt * 32 + (L & 15);   // col = colb + c*16, c in 0..3
        float r4[2][4];
        #pragma unroll
        for (int i = 0; i < 2; ++i) {
            #pragma unroll
            for (int r = 0; r < 4; ++r) r4[i][r] = 1e30f;
            #pragma unroll
            for (int c = 0; c < 4; ++c)
                #pragma unroll
                for (int r = 0; r < 4; ++r)
                    r4[i][r] = fminf(r4[i][r], fmaf(-2.f, acc[i][c][r], t2v[c]));
        }

        // threshold base (subset-min of the row's bf16 scores: safe with MARGIN >= 2E)
        float thb[2][4];
        if (nt == t0) {
            // seed: butterfly first-pair row-min FIRST so t0 capture doesn't flood
            #pragma unroll
            for (int i = 0; i < 2; ++i)
                #pragma unroll
                for (int r = 0; r < 4; ++r) rowmin_reg[i][r] = r4[i][r];
            #pragma unroll
            for (int st = 1; st <= 8; st <<= 1)
                #pragma unroll
                for (int i = 0; i < 2; ++i)
                    #pragma unroll
                    for (int r = 0; r < 4; ++r)
                        rowmin_reg[i][r] = fminf(rowmin_reg[i][r], __shfl_xor(rowmin_reg[i][r], st, 64));
            #pragma unroll
            for (int i = 0; i < 2; ++i)
                #pragma unroll
                for (int r = 0; r < 4; ++r) thb[i][r] = rowmin_reg[i][r];
        } else {
            #pragma unroll
            for (int i = 0; i < 2; ++i)
                #pragma unroll
                for (int r = 0; r < 4; ++r) thb[i][r] = fminf(rowmin_reg[i][r], r4[i][r]);
        }

        bool anyhit = false;
        #pragma unroll
        for (int i = 0; i < 2; ++i)
            #pragma unroll
            for (int r = 0; r < 4; ++r)
                anyhit = anyhit || (r4[i][r] < thb[i][r] + MARGIN);

        if (__any(anyhit)) {
            u32 cnt = 0;
            #pragma unroll
            for (int i = 0; i < 2; ++i)
                #pragma unroll
                for (int r = 0; r < 4; ++r) {
                    float th = thb[i][r] + MARGIN;
                    if (r4[i][r] < th) {
                        #pragma unroll
                        for (int c = 0; c < 4; ++c)
                            cnt += (fmaf(-2.f, acc[i][c][r], t2v[c]) < th) ? 1u : 0u;
                    }
                }
            u32 pre = cnt;
            #pragma unroll
            for (int d = 1; d < 64; d <<= 1) {
                u32 v = __shfl_up(pre, d, 64);
                if (L >= d) pre += v;
            }
            u32 total = __shfl(pre, 63, 64);
            u32 woff = wcount + pre - cnt;
            #pragma unroll
            for (int i = 0; i < 2; ++i)
                #pragma unroll
                for (int r = 0; r < 4; ++r) {
                    float th = thb[i][r] + MARGIN;
                    if (r4[i][r] < th) {
                        const int q = mb * 256 + w * 32 + i * 16 + (L >> 4) * 4 + r;
                        #pragma unroll
                        for (int c = 0; c < 4; ++c) {
                            float s = fmaf(-2.f, acc[i][c][r], t2v[c]);
                            if (s < th) {
                                if (woff < WCAP)
                                    wreg[woff] = ((u64)__float_as_uint(s) << 32)
                                               | (u64)(((u32)q << 16) | (u32)(colb + c * 16));
                                woff++;
                            }
                        }
                    }
                }
            wcount += total;
        }

        // fold per-lane; full 16-lane butterfly every 2nd pair (= every 4 half-tiles)
        #pragma unroll
        for (int i = 0; i < 2; ++i)
            #pragma unroll
            for (int r = 0; r < 4; ++r)
                rowmin_reg[i][r] = fminf(rowmin_reg[i][r], r4[i][r]);
        if (((nt - t0) & 2) == 2) {
            #pragma unroll
            for (int st = 1; st <= 8; st <<= 1)
                #pragma unroll
                for (int i = 0; i < 2; ++i)
                    #pragma unroll
                    for (int r = 0; r < 4; ++r)
                        rowmin_reg[i][r] = fminf(rowmin_reg[i][r], __shfl_xor(rowmin_reg[i][r], st, 64));
        }

        __syncthreads();   // drains pair prefetch + protects buffer reuse (1 barrier / 2 tiles)
    }

    // ---- final: exact chunk row-min -> global gmin atomics + candidate count ----
    #pragma unroll
    for (int st = 1; st <= 8; st <<= 1)
        #pragma unroll
        for (int i = 0; i < 2; ++i)
            #pragma unroll
            for (int r = 0; r < 4; ++r)
                rowmin_reg[i][r] = fminf(rowmin_reg[i][r], __shfl_xor(rowmin_reg[i][r], st, 64));
    if ((L & 15) == 0) {
        #pragma unroll
        for (int i = 0; i < 2; ++i)
            #pragma unroll
            for (int r = 0; r < 4; ++r) {
                int q = mb * 256 + w * 32 + i * 16 + (L >> 4) * 4 + r;
                atomicMin(&gminu[q], ordf(rowmin_reg[i][r]));
            }
    }
    if (L == 0) wavecnt[gwave] = (wcount < WCAP) ? wcount : WCAP;
    #undef STAGE
    #undef TBASE_U32
}

// ---------------- filtered exact fp32 rescore: ballot-compacted, wave-cooperative ----------------
__global__ void rescore(const float* __restrict__ x, const float* __restrict__ Xt,
                        const float* __restrict__ t2, const u32* __restrict__ gminu,
                        const u32* __restrict__ wavecnt, const u64* __restrict__ cands,
                        u64* __restrict__ best) {
    const int L = threadIdx.x & 63;
    const int gw = blockIdx.x * (blockDim.x >> 6) + (threadIdx.x >> 6);
    if (gw >= NWAVE_CAP) return;
    u32 cnt = wavecnt[gw];
    if (cnt > WCAP) cnt = WCAP;
    const u64* reg = cands + (size_t)gw * WCAP;
    for (u32 base = 0; base < cnt; base += 64) {
        u32 i = base + L;
        u64 rec = 0; bool pass = false;
        if (i < cnt) {
            rec = reg[i];                                   // coalesced 512 B
            float sb = __uint_as_float((u32)(rec >> 32));
            int q = (int)((rec >> 16) & 0xFFFFu);
            pass = sb < iordf(gminu[q]) + FMARGIN;
        }
        u64 bal = __ballot(pass);
        while (bal) {
            int j = __ffsll((unsigned long long)bal) - 1;
            bal &= bal - 1;
            u64 r2 = __shfl(rec, j, 64);
            int q = (int)((r2 >> 16) & 0xFFFFu);
            int n = (int)(r2 & 0xFFFFu);
            float4 a = *((const float4*)(x  + (size_t)q * F_DIM) + L);
            float4 b = *((const float4*)(Xt + (size_t)n * F_DIM) + L);
            float d = fmaf(a.x, b.x, fmaf(a.y, b.y, fmaf(a.z, b.z, a.w * b.w)));
            #pragma unroll
            for (int st = 32; st > 0; st >>= 1) d += __shfl_xor(d, st, 64);
            if (L == 0) {
                float s = fmaf(-2.f, d, t2[n]);
                u64 p = ((u64)ordf(s) << 32) | (u32)n;
                atomicMin(&best[q], p);
            }
        }
    }
}

// ---------------- gather Y[nearest] ----------------
__global__ void gather_kernel(const float* __restrict__ Y, const u64* __restrict__ best,
                              float* __restrict__ out, int B, int N) {
    int gid = blockIdx.x * blockDim.x + threadIdx.x;
    int total = B * O_DIM;
    if (gid >= total) return;
    int b = gid / O_DIM;
    int o = gid - b * O_DIM;
    u32 n = (u32)(best[b] & 0xFFFFFFFFull);
    if (n >= (u32)N) n = 0;   // defensive
    out[gid] = Y[(size_t)n * O_DIM + o];
}

// ================= fp32 fallback (proven Round-1 path, used if ws too small) =================
#define BM 128
#define BN 128
#define BK 16
#define NSPLIT 64
#define LDA (BM + 4)

__global__ __launch_bounds__(256) void knn_main_fp32(
    const float* __restrict__ Xq, const float* __restrict__ Xt,
    const float* __restrict__ t2, u64* __restrict__ best, int N)
{
    __shared__ float As[BK][LDA];
    __shared__ float Bs[BK][LDA];
    __shared__ u64 red[BM][17];

    const int tid = threadIdx.x;
    const int tx = tid & 15;
    const int ty = tid >> 4;
    const int m0 = blockIdx.y * BM;
    const int CHUNK = (N + NSPLIT - 1) / NSPLIT;
    const int n0c = blockIdx.x * CHUNK;
    const int n1c = min(N, n0c + CHUNK);

    u64 bestv[8];
    #pragma unroll
    for (int i = 0; i < 8; ++i) bestv[i] = ~0ull;

    const int srow = tid >> 2;
    const int scol4 = (tid & 3) * 4;

    for (int nt = n0c; nt < n1c; nt += BN) {
        float accl[8][8];
        #pragma unroll
        for (int i = 0; i < 8; ++i)
            #pragma unroll
            for (int j = 0; j < 8; ++j) accl[i][j] = 0.f;
        for (int k0 = 0; k0 < F_DIM; k0 += BK) {
            #pragma unroll
            for (int h = 0; h < 2; ++h) {
                int row = h * 64 + srow;
                float4 av = *(const float4*)(Xq + (size_t)(m0 + row) * F_DIM + k0 + scol4);
                As[scol4 + 0][row] = av.x; As[scol4 + 1][row] = av.y;
                As[scol4 + 2][row] = av.z; As[scol4 + 3][row] = av.w;
                int n = nt + row;
                float4 bv = make_float4(0.f, 0.f, 0.f, 0.f);
                if (n < n1c) bv = *(const float4*)(Xt + (size_t)n * F_DIM + k0 + scol4);
                Bs[scol4 + 0][row] = bv.x; Bs[scol4 + 1][row] = bv.y;
                Bs[scol4 + 2][row] = bv.z; Bs[scol4 + 3][row] = bv.w;
            }
            __syncthreads();
            #pragma unroll
            for (int k = 0; k < BK; ++k) {
                float4 a0 = *(const float4*)&As[k][ty * 4];
                float4 a1 = *(const float4*)&As[k][64 + ty * 4];
                float4 b0 = *(const float4*)&Bs[k][tx * 4];
                float4 b1 = *(const float4*)&Bs[k][64 + tx * 4];
                float am[8] = {a0.x, a0.y, a0.z, a0.w, a1.x, a1.y, a1.z, a1.w};
                float bn[8] = {b0.x, b0.y, b0.z, b0.w, b1.x, b1.y, b1.z, b1.w};
                #pragma unroll
                for (int i = 0; i < 8; ++i)
                    #pragma unroll
                    for (int j = 0; j < 8; ++j)
                        accl[i][j] = fmaf(am[i], bn[j], accl[i][j]);
            }
            __syncthreads();
        }
        #pragma unroll
        for (int j = 0; j < 8; ++j) {
            int nl = (j < 4) ? (tx * 4 + j) : (64 + tx * 4 + (j - 4));
            int n = nt + nl;
            if (n < n1c) {
                float t2v = t2[n];
                #pragma unroll
                for (int i = 0; i < 8; ++i) {
                    float score = fmaf(-2.f, accl[i][j], t2v);
                    u64 p = ((u64)ordf(score) << 32) | (u32)n;
                    bestv[i] = (p < bestv[i]) ? p : bestv[i];
                }
            }
        }
    }
    #pragma unroll
    for (int i = 0; i < 8; ++i) {
        int ml = (i < 4) ? (ty * 4 + i) : (64 + ty * 4 + (i - 4));
        red[ml][tx] = bestv[i];
    }
    __syncthreads();
    if (tid < BM) {
        u64 b = red[tid][0];
        #pragma unroll
        for (int t = 1; t < 16; ++t) { u64 v = red[tid][t]; b = (v < b) ? v : b; }
        atomicMin(&best[m0 + tid], b);
    }
}

// ================= launch =================
extern "C" void kernel_launch(void* const* d_in, const int* in_sizes, int n_in,
                              void* d_out, int out_size, void* d_ws, size_t ws_size,
                              hipStream_t stream) {
    const float* x  = (const float*)d_in[0];
    const float* Xt = (const float*)d_in[1];
    const float* Yt = (const float*)d_in[2];
    float* out = (float*)d_out;

    const int B = in_sizes[0] / F_DIM;        // 2048
    const int N = in_sizes[1] / F_DIM;        // 50000
    const int NT128 = (N + 127) / 128;        // 391
    const int Npad = NT128 * 128;             // 50048
    const int NT64 = NT128 * 2;               // 782
    const int NT32 = NT64 * 2;                // 1564
    const int MB = B / 256;                   // 8
    const int MT128 = B / 128;                // 16
    const int NCH = 64;                       // 8*64 = 512 blocks = 2/CU (512 thr each)

    char* wsp = (char*)d_ws;
    size_t off = 0;
    auto nxt = [&](size_t bytes) {
        char* p = wsp + off;
        off = (off + bytes + 255) & ~(size_t)255;
        return p;
    };
    float* t2       = (float*)nxt((size_t)Npad * 4);
    u64*   best     = (u64*)  nxt((size_t)B * 8);
    u32*   wavecnt  = (u32*)  nxt((size_t)NWAVE_CAP * 4);
    u32*   gminu    = (u32*)  nxt((size_t)B * 4);
    u64*   cands    = (u64*)  nxt((size_t)NWAVE_CAP * WCAP * 8);
    u16*   xbf      = (u16*)  nxt((size_t)B * F_DIM * 2);
    u16*   xtbf     = (u16*)  nxt((size_t)Npad * F_DIM * 2);
    size_t required = off;

    if (ws_size >= required && B % 256 == 0 && MB * NCH * 8 <= NWAVE_CAP) {
        // 4 launches: convert_dual(x+Xt, fused init+t2), knn_mfma(+gmin atomics), rescore, gather
        convert_dual<<<dim3(MT128 + NT128, 4), 256, 0, stream>>>(
            x, xbf, B, Xt, xtbf, t2, N, MT128, best, gminu);
        knn_mfma<<<dim3(MB * NCH), 512, 0, stream>>>(xbf, xtbf, t2, gminu, wavecnt, cands, NT32, NCH);
        rescore<<<NWAVE_CAP / 4, 256, 0, stream>>>(x, Xt, t2, gminu, wavecnt, cands, best);
    } else {
        init_kernel<<<(B + 255) / 256, 256, 0, stream>>>(best, (u32*)nullptr, B);
        t2_kernel<<<(N + 3) / 4, 256, 0, stream>>>(Xt, t2, N, N);
        dim3 grid(NSPLIT, B / BM);
        knn_main_fp32<<<grid, 256, 0, stream>>>(x, Xt, t2, best, N);
    }

    int total = B * O_DIM;
    gather_kernel<<<(total + 255) / 256, 256, 0, stream>>>(Yt, best, out, B, N);
}